// Round 6
// baseline (489.963 us; speedup 1.0000x reference)
//
#include <hip/hip_runtime.h>

typedef short bf16x8 __attribute__((ext_vector_type(8)));
typedef float f32x4  __attribute__((ext_vector_type(4)));
typedef unsigned short ushort_t;

__device__ __forceinline__ float silu(float x) {
    float t = __expf(-x);
    return x * __builtin_amdgcn_rcpf(1.f + t);
}

__device__ __forceinline__ ushort_t f2bs(float x) {
    union { float f; unsigned int u; } v; v.f = x;
    unsigned int r = v.u + 0x7FFF + ((v.u >> 16) & 1);
    return (ushort_t)(r >> 16);
}
__device__ __forceinline__ ushort_t f2bs_t(float x) {
    union { float f; unsigned int u; } v; v.f = x;
    return (ushort_t)(v.u >> 16);
}
__device__ __forceinline__ float bs2f(ushort_t x) {
    union { unsigned int u; float f; } v; v.u = ((unsigned int)x) << 16; return v.f;
}

constexpr int N_   = 16000;
constexpr int E_   = 256000;
constexpr int Fd   = 64;

constexpr float SQ3f    = 1.7320508075688772f;
constexpr float INV_SQ3 = 0.5773502691896258f;
constexpr float INV_SQ2 = 0.7071067811865476f;
constexpr float INV_AVG = 0.0625f;

constexpr int OFF_OS = 0;
constexpr int OFF_OV = N_;
constexpr int OFF_PS = OFF_OV + 3 * N_;
constexpr int OFF_PV = OFF_PS + N_ * Fd;

constexpr int W1P_SZ = 6 * 8 * 512;
constexpr int W2P_SZ = 4 * 8 * 512;
constexpr int W3P_SZ = 4 * 12 * 512;

// ---------------------------------------------------------------------------
// pack weights fp32 -> bf16 MFMA B-fragment order
// ---------------------------------------------------------------------------
__global__ __launch_bounds__(256) void pack_kernel(
    const float* __restrict__ W1, const float* __restrict__ W2,
    const float* __restrict__ W3,
    ushort_t* __restrict__ W1p, ushort_t* __restrict__ W2p,
    ushort_t* __restrict__ W3p)
{
    int idx = blockIdx.x * 256 + threadIdx.x;
    if (idx < W1P_SZ) {
        int j = idx & 7, lane = (idx >> 3) & 63, tile = idx >> 9;
        int c = tile >> 3, t = tile & 7;
        int k = c * 32 + (lane >> 4) * 8 + j;
        int n = t * 16 + (lane & 15);
        W1p[idx] = f2bs(k < 161 ? W1[k * 128 + n] : 0.f);
    } else if (idx < W1P_SZ + W2P_SZ) {
        int q = idx - W1P_SZ;
        int j = q & 7, lane = (q >> 3) & 63, tile = q >> 9;
        int c = tile >> 3, t = tile & 7;
        int k = c * 32 + (lane >> 4) * 8 + j;
        int n = t * 16 + (lane & 15);
        W2p[q] = f2bs(W2[k * 128 + n]);
    } else {
        int q = idx - W1P_SZ - W2P_SZ;
        int j = q & 7, lane = (q >> 3) & 63, tile = q >> 9;
        int c = tile / 12, t = tile % 12;
        int k = c * 32 + (lane >> 4) * 8 + j;
        int n = t * 16 + (lane & 15);
        W3p[q] = f2bs(W3[k * 192 + n]);
    }
}

// ---------------------------------------------------------------------------
// Kernel 1: up-projection, 4 nodes/block (weights read once per block).
// h_s bf16; h_v fp32 SoA h_v[n*192 + c*64 + g]. Fused receiver-count.
// ---------------------------------------------------------------------------
__global__ __launch_bounds__(64, 4) void up_kernel(
    const float* __restrict__ node_s, const float* __restrict__ node_v,
    const float* __restrict__ W_up_s, const float* __restrict__ b_up_s,
    const float* __restrict__ W_up_v,
    const int* __restrict__ receivers, int* __restrict__ cnt,
    ushort_t* __restrict__ hs_bf, float* __restrict__ h_v)
{
    __shared__ float ns[4][64];
    __shared__ float nv[4][64][3];
    const int n0 = blockIdx.x * 4;
    const int g  = threadIdx.x;

    {   // fused receiver count: 64 edges per block (E = 16*N)
        int e = blockIdx.x * 64 + g;
        atomicAdd(&cnt[receivers[e]], 1);
    }

    #pragma unroll
    for (int j = 0; j < 4; j++) ns[j][g] = node_s[(n0 + j) * 64 + g];
    for (int idx = g; idx < 4 * 192; idx += 64) {
        int j = idx / 192, r = idx - j * 192;
        nv[j][r / 3][r % 3] = node_v[(size_t)n0 * 192 + idx];
    }
    __syncthreads();

    float as[4], a0[4], a1[4], a2[4];
    float bb = b_up_s[g];
    #pragma unroll
    for (int j = 0; j < 4; j++) { as[j] = bb; a0[j] = a1[j] = a2[j] = 0.f; }
    #pragma unroll 4
    for (int f = 0; f < 64; f++) {
        float wss = W_up_s[f * 64 + g];
        float wv  = W_up_v[f * 64 + g];
        #pragma unroll
        for (int j = 0; j < 4; j++) {
            as[j] += ns[j][f] * wss;
            a0[j] += nv[j][f][0] * wv;
            a1[j] += nv[j][f][1] * wv;
            a2[j] += nv[j][f][2] * wv;
        }
    }
    #pragma unroll
    for (int j = 0; j < 4; j++) {
        hs_bf[(n0 + j) * 64 + g] = f2bs(as[j]);
        h_v[(n0 + j) * 192 + 0 * 64 + g] = a0[j];
        h_v[(n0 + j) * 192 + 1 * 64 + g] = a1[j];
        h_v[(n0 + j) * 192 + 2 * 64 + g] = a2[j];
    }
}

// ---------------------------------------------------------------------------
// CSR scan
// ---------------------------------------------------------------------------
__global__ __launch_bounds__(1024) void scan_kernel(
    const int* __restrict__ cnt, int* __restrict__ base, int* __restrict__ cursor)
{
    __shared__ int part[1024];
    const int t = threadIdx.x;
    int v[16];
    int s = 0;
    if (t < 1000) {
        const int4* c4 = (const int4*)(cnt + t * 16);
        #pragma unroll
        for (int q = 0; q < 4; q++) {
            int4 w = c4[q];
            v[q * 4 + 0] = w.x; v[q * 4 + 1] = w.y;
            v[q * 4 + 2] = w.z; v[q * 4 + 3] = w.w;
            s += w.x + w.y + w.z + w.w;
        }
    }
    part[t] = s;
    __syncthreads();
    for (int off = 1; off < 1024; off <<= 1) {
        int u = (t >= off) ? part[t - off] : 0;
        __syncthreads();
        part[t] += u;
        __syncthreads();
    }
    if (t < 1000) {
        int run = part[t] - s;
        int b[16];
        #pragma unroll
        for (int i = 0; i < 16; i++) { b[i] = run; run += v[i]; }
        int4* bb = (int4*)(base + t * 16);
        int4* cc = (int4*)(cursor + t * 16);
        #pragma unroll
        for (int q = 0; q < 4; q++) {
            int4 w = { b[q * 4], b[q * 4 + 1], b[q * 4 + 2], b[q * 4 + 3] };
            bb[q] = w;
            cc[q] = w;
        }
    }
}

// ---------------------------------------------------------------------------
// Kernel 2: MFMA edge MLP, M=32 edges/wave (B-fragments amortized 2x).
// 128 threads = 2 waves, 64 edges/block. Fused CSR scatter.
// ---------------------------------------------------------------------------
__global__ __launch_bounds__(128, 2) void edge_mlp_kernel(
    const float* __restrict__ lengths, const float* __restrict__ sef,
    const int* __restrict__ senders, const int* __restrict__ receivers,
    const float* __restrict__ b1f, const float* __restrict__ b2f,
    const float* __restrict__ b3f,
    const ushort_t* __restrict__ hs_bf,
    const ushort_t* __restrict__ W1p, const ushort_t* __restrict__ W2p,
    const ushort_t* __restrict__ W3p,
    int* __restrict__ cursor, int* __restrict__ sorted_eid,
    ushort_t* __restrict__ tpx)
{
    __shared__ ushort_t Hs[64 * 136];   // 17.4 KB (2 waves x 32 rows)

    const int tid  = threadIdx.x;
    const int wave = tid >> 6, lane = tid & 63;
    const int quad = lane >> 4, l4 = lane & 15;
    const int ebase = blockIdx.x * 64 + wave * 32;
    const int me0   = ebase + l4;
    const int me1   = ebase + 16 + l4;
    const int hrow  = wave * 32;

    if (tid < 64) {
        int e = blockIdx.x * 64 + tid;
        int p = atomicAdd(&cursor[receivers[e]], 1);
        sorted_eid[p] = e;
    }

    const int snd0 = senders[me0], rcv0 = receivers[me0];
    const int snd1 = senders[me1], rcv1 = receivers[me1];

    bf16x8 a0[6], a1[6];
    a0[0] = *(const bf16x8*)(hs_bf + snd0 * 64 + quad * 8);
    a0[1] = *(const bf16x8*)(hs_bf + snd0 * 64 + 32 + quad * 8);
    a0[2] = *(const bf16x8*)(hs_bf + rcv0 * 64 + quad * 8);
    a0[3] = *(const bf16x8*)(hs_bf + rcv0 * 64 + 32 + quad * 8);
    a1[0] = *(const bf16x8*)(hs_bf + snd1 * 64 + quad * 8);
    a1[1] = *(const bf16x8*)(hs_bf + snd1 * 64 + 32 + quad * 8);
    a1[2] = *(const bf16x8*)(hs_bf + rcv1 * 64 + quad * 8);
    a1[3] = *(const bf16x8*)(hs_bf + rcv1 * 64 + 32 + quad * 8);
    {
        const float4 s0 = *(const float4*)(sef + (size_t)me0 * 32 + quad * 8);
        const float4 s1 = *(const float4*)(sef + (size_t)me0 * 32 + quad * 8 + 4);
        bf16x8 t;
        t[0] = (short)f2bs(s0.x); t[1] = (short)f2bs(s0.y);
        t[2] = (short)f2bs(s0.z); t[3] = (short)f2bs(s0.w);
        t[4] = (short)f2bs(s1.x); t[5] = (short)f2bs(s1.y);
        t[6] = (short)f2bs(s1.z); t[7] = (short)f2bs(s1.w);
        a0[4] = t;
        const float4 u0 = *(const float4*)(sef + (size_t)me1 * 32 + quad * 8);
        const float4 u1 = *(const float4*)(sef + (size_t)me1 * 32 + quad * 8 + 4);
        t[0] = (short)f2bs(u0.x); t[1] = (short)f2bs(u0.y);
        t[2] = (short)f2bs(u0.z); t[3] = (short)f2bs(u0.w);
        t[4] = (short)f2bs(u1.x); t[5] = (short)f2bs(u1.y);
        t[6] = (short)f2bs(u1.z); t[7] = (short)f2bs(u1.w);
        a1[4] = t;
    }
    {
        bf16x8 t = {0,0,0,0,0,0,0,0};
        bf16x8 u = {0,0,0,0,0,0,0,0};
        if (quad == 0) { t[0] = (short)f2bs(lengths[me0]); u[0] = (short)f2bs(lengths[me1]); }
        a0[5] = t; a1[5] = u;
    }

    const bf16x8* B1 = (const bf16x8*)W1p;
    const bf16x8* B2 = (const bf16x8*)W2p;
    const bf16x8* B3 = (const bf16x8*)W3p;

    // GEMM1
    f32x4 accA[8], accB[8];
    #pragma unroll
    for (int t = 0; t < 8; t++) { accA[t] = (f32x4){0,0,0,0}; accB[t] = (f32x4){0,0,0,0}; }
    #pragma unroll
    for (int c = 0; c < 6; c++) {
        #pragma unroll
        for (int t = 0; t < 8; t++) {
            bf16x8 b = B1[(c * 8 + t) * 64 + lane];
            accA[t] = __builtin_amdgcn_mfma_f32_16x16x32_bf16(a0[c], b, accA[t], 0, 0, 0);
            accB[t] = __builtin_amdgcn_mfma_f32_16x16x32_bf16(a1[c], b, accB[t], 0, 0, 0);
        }
    }
    #pragma unroll
    for (int t = 0; t < 8; t++) {
        float bb = b1f[t * 16 + l4];
        #pragma unroll
        for (int r = 0; r < 4; r++) {
            Hs[(hrow + quad * 4 + r) * 136 + t * 16 + l4]      = f2bs_t(silu(accA[t][r] + bb));
            Hs[(hrow + 16 + quad * 4 + r) * 136 + t * 16 + l4] = f2bs_t(silu(accB[t][r] + bb));
        }
    }

    // GEMM2
    #pragma unroll
    for (int t = 0; t < 8; t++) { accA[t] = (f32x4){0,0,0,0}; accB[t] = (f32x4){0,0,0,0}; }
    #pragma unroll
    for (int c = 0; c < 4; c++) {
        bf16x8 af0 = *(const bf16x8*)(&Hs[(hrow + l4) * 136 + c * 32 + quad * 8]);
        bf16x8 af1 = *(const bf16x8*)(&Hs[(hrow + 16 + l4) * 136 + c * 32 + quad * 8]);
        #pragma unroll
        for (int t = 0; t < 8; t++) {
            bf16x8 b = B2[(c * 8 + t) * 64 + lane];
            accA[t] = __builtin_amdgcn_mfma_f32_16x16x32_bf16(af0, b, accA[t], 0, 0, 0);
            accB[t] = __builtin_amdgcn_mfma_f32_16x16x32_bf16(af1, b, accB[t], 0, 0, 0);
        }
    }
    #pragma unroll
    for (int t = 0; t < 8; t++) {
        float bb = b2f[t * 16 + l4];
        #pragma unroll
        for (int r = 0; r < 4; r++) {
            Hs[(hrow + quad * 4 + r) * 136 + t * 16 + l4]      = f2bs_t(silu(accA[t][r] + bb));
            Hs[(hrow + 16 + quad * 4 + r) * 136 + t * 16 + l4] = f2bs_t(silu(accB[t][r] + bb));
        }
    }

    // GEMM3
    f32x4 acc3A[12], acc3B[12];
    #pragma unroll
    for (int t = 0; t < 12; t++) { acc3A[t] = (f32x4){0,0,0,0}; acc3B[t] = (f32x4){0,0,0,0}; }
    #pragma unroll
    for (int c = 0; c < 4; c++) {
        bf16x8 af0 = *(const bf16x8*)(&Hs[(hrow + l4) * 136 + c * 32 + quad * 8]);
        bf16x8 af1 = *(const bf16x8*)(&Hs[(hrow + 16 + l4) * 136 + c * 32 + quad * 8]);
        #pragma unroll
        for (int t = 0; t < 12; t++) {
            bf16x8 b = B3[(c * 12 + t) * 64 + lane];
            acc3A[t] = __builtin_amdgcn_mfma_f32_16x16x32_bf16(af0, b, acc3A[t], 0, 0, 0);
            acc3B[t] = __builtin_amdgcn_mfma_f32_16x16x32_bf16(af1, b, acc3B[t], 0, 0, 0);
        }
    }
    #pragma unroll
    for (int t = 0; t < 12; t++) {
        float bb = b3f[t * 16 + l4];
        #pragma unroll
        for (int r = 0; r < 4; r++) {
            tpx[(size_t)(ebase + quad * 4 + r) * 192 + t * 16 + l4]      = f2bs(acc3A[t][r] + bb);
            tpx[(size_t)(ebase + 16 + quad * 4 + r) * 192 + t * 16 + l4] = f2bs(acc3B[t][r] + bb);
        }
    }
}

// ---------------------------------------------------------------------------
// Kernel 3: CSR aggregation + node tail, 4 nodes/block (weights amortized 4x).
// ---------------------------------------------------------------------------
__global__ __launch_bounds__(64, 4) void node_fused_kernel(
    const int* __restrict__ base, const int* __restrict__ cnt,
    const int* __restrict__ sorted_eid, const int* __restrict__ senders,
    const float* __restrict__ vectors,
    const ushort_t* __restrict__ tpx,
    const ushort_t* __restrict__ hs_bf, const float* __restrict__ h_v,
    const int* __restrict__ specie,
    const float* __restrict__ W_dn_s, const float* __restrict__ b_dn_s,
    const float* __restrict__ W_dn_v,
    const float* __restrict__ w_sc_s, const float* __restrict__ w_sc_v,
    const float* __restrict__ W_pb_s, const float* __restrict__ b_pb_s,
    const float* __restrict__ W_pb_v,
    const float* __restrict__ W_r1_s, const float* __restrict__ b_r1_s,
    const float* __restrict__ W_r1_v,
    const float* __restrict__ W_r2_s, const float* __restrict__ b_r2,
    const float* __restrict__ W_r2_v,
    float* __restrict__ out)
{
    __shared__ float as_l[4][64];
    __shared__ float av_l[4][128][3];
    __shared__ float scs[4][64];
    __shared__ float scv[4][64][3];
    __shared__ float ps_[4][64];
    __shared__ float pv_[4][64][3];
    __shared__ int   eids[64];

    const int n0 = blockIdx.x * 4;
    const int g  = threadIdx.x;

    // ---- aggregation, one node at a time ----
    for (int j = 0; j < 4; j++) {
        const int n = n0 + j;
        const int b = base[n];
        const int c = cnt[n];
        float accS = 0.f;
        float a10 = 0.f, a11 = 0.f, a12 = 0.f;
        float a20 = 0.f, a21 = 0.f, a22 = 0.f;

        for (int done = 0; done < c; done += 64) {
            int m = min(64, c - done);
            __syncthreads();
            if (g < m) eids[g] = sorted_eid[b + done + g];
            __syncthreads();
            for (int i = 0; i < m; i++) {
                const int e  = eids[i];
                const int se = senders[e];
                const float ev0 = SQ3f * vectors[e * 3 + 0];
                const float ev1 = SQ3f * vectors[e * 3 + 1];
                const float ev2 = SQ3f * vectors[e * 3 + 2];
                const float mv0 = h_v[(size_t)se * 192 + 0 * 64 + g];
                const float mv1 = h_v[(size_t)se * 192 + 1 * 64 + g];
                const float mv2 = h_v[(size_t)se * 192 + 2 * 64 + g];
                const float m_s = bs2f(hs_bf[se * 64 + g]);
                const ushort_t* mrow = tpx + (size_t)e * 192;
                const float c0 = bs2f(mrow[g]);
                const float c1 = bs2f(mrow[64 + g]);
                const float c2 = bs2f(mrow[128 + g]);

                float dot = mv0 * ev0 + mv1 * ev1 + mv2 * ev2;
                accS += dot * c0;
                float k1 = m_s * c1;
                a10 += k1 * ev0; a11 += k1 * ev1; a12 += k1 * ev2;
                a20 += (mv1 * ev2 - mv2 * ev1) * c2;
                a21 += (mv2 * ev0 - mv0 * ev2) * c2;
                a22 += (mv0 * ev1 - mv1 * ev0) * c2;
            }
        }
        as_l[j][g] = accS * (INV_SQ3 * INV_AVG);
        av_l[j][g][0] = a10 * INV_AVG;
        av_l[j][g][1] = a11 * INV_AVG;
        av_l[j][g][2] = a12 * INV_AVG;
        av_l[j][64 + g][0] = a20 * (INV_SQ2 * INV_AVG);
        av_l[j][64 + g][1] = a21 * (INV_SQ2 * INV_AVG);
        av_l[j][64 + g][2] = a22 * (INV_SQ2 * INV_AVG);
    }
    __syncthreads();

    // ---- tail: weights loaded once, applied to 4 nodes ----
    float f_s[4];
    {
        float bb = b_dn_s[g];
        #pragma unroll
        for (int j = 0; j < 4; j++) f_s[j] = bb;
    }
    #pragma unroll 4
    for (int f = 0; f < 64; f++) {
        float w = W_dn_s[f * 64 + g];
        #pragma unroll
        for (int j = 0; j < 4; j++) f_s[j] += as_l[j][f] * w;
    }
    float fv[4][3] = {};
    #pragma unroll 4
    for (int f = 0; f < 128; f++) {
        float w = W_dn_v[f * 64 + g];
        #pragma unroll
        for (int j = 0; j < 4; j++) {
            fv[j][0] += av_l[j][f][0] * w;
            fv[j][1] += av_l[j][f][1] * w;
            fv[j][2] += av_l[j][f][2] * w;
        }
    }

    #pragma unroll
    for (int j = 0; j < 4; j++) {
        float vv = (fv[j][0]*fv[j][0] + fv[j][1]*fv[j][1] + fv[j][2]*fv[j][2]) * INV_SQ3;
        int sp = specie[n0 + j];
        float ws0 = w_sc_s[sp * 192 + 0 * 64 + g];
        float ws1 = w_sc_s[sp * 192 + 1 * 64 + g];
        float ws2 = w_sc_s[sp * 192 + 2 * 64 + g];
        float wv0 = w_sc_v[sp * 128 + 0 * 64 + g];
        float wv1 = w_sc_v[sp * 128 + 1 * 64 + g];
        float sc = ws0 * f_s[j] + ws1 * f_s[j] * f_s[j] + ws2 * vv;
        float kv = wv0 + wv1 * f_s[j];
        scs[j][g] = sc;
        scv[j][g][0] = kv * fv[j][0];
        scv[j][g][1] = kv * fv[j][1];
        scv[j][g][2] = kv * fv[j][2];
    }
    __syncthreads();

    float p_s[4], pv[4][3] = {};
    {
        float bb = b_pb_s[g];
        #pragma unroll
        for (int j = 0; j < 4; j++) p_s[j] = bb;
    }
    #pragma unroll 4
    for (int f = 0; f < 64; f++) {
        float wps = W_pb_s[f * 64 + g];
        float wpv = W_pb_v[f * 64 + g];
        #pragma unroll
        for (int j = 0; j < 4; j++) {
            p_s[j] += scs[j][f] * wps;
            pv[j][0] += scv[j][f][0] * wpv;
            pv[j][1] += scv[j][f][1] * wpv;
            pv[j][2] += scv[j][f][2] * wpv;
        }
    }
    #pragma unroll
    for (int j = 0; j < 4; j++) {
        ps_[j][g] = p_s[j];
        pv_[j][g][0] = pv[j][0]; pv_[j][g][1] = pv[j][1]; pv_[j][g][2] = pv[j][2];
        out[OFF_PS + (n0 + j) * 64 + g] = p_s[j];
        out[OFF_PV + (size_t)(n0 + j) * 192 + g * 3 + 0] = pv[j][0];
        out[OFF_PV + (size_t)(n0 + j) * 192 + g * 3 + 1] = pv[j][1];
        out[OFF_PV + (size_t)(n0 + j) * 192 + g * 3 + 2] = pv[j][2];
    }
    __syncthreads();

    float r0[4], r1[4], rv[4][3] = {};
    {
        float bb0 = b_r1_s[g], bb1 = b_r1_s[g + 64];
        #pragma unroll
        for (int j = 0; j < 4; j++) { r0[j] = bb0; r1[j] = bb1; }
    }
    #pragma unroll 4
    for (int f = 0; f < 64; f++) {
        float w0 = W_r1_s[f * 128 + g];
        float w1 = W_r1_s[f * 128 + g + 64];
        float wv = W_r1_v[f * 64 + g];
        #pragma unroll
        for (int j = 0; j < 4; j++) {
            float p = ps_[j][f];
            r0[j] += p * w0;
            r1[j] += p * w1;
            rv[j][0] += pv_[j][f][0] * wv;
            rv[j][1] += pv_[j][f][1] * wv;
            rv[j][2] += pv_[j][f][2] * wv;
        }
    }
    float wr2s = W_r2_s[g], wr2v = W_r2_v[g];
    #pragma unroll
    for (int j = 0; j < 4; j++) {
        float o_s = silu(r0[j]) * wr2s;
        float gate = silu(r1[j]);
        float ov0 = gate * rv[j][0] * wr2v;
        float ov1 = gate * rv[j][1] * wr2v;
        float ov2 = gate * rv[j][2] * wr2v;
        #pragma unroll
        for (int off = 32; off > 0; off >>= 1) {
            o_s += __shfl_down(o_s, off);
            ov0 += __shfl_down(ov0, off);
            ov1 += __shfl_down(ov1, off);
            ov2 += __shfl_down(ov2, off);
        }
        if (g == 0) {
            out[OFF_OS + n0 + j] = o_s + b_r2[0];
            out[OFF_OV + (n0 + j) * 3 + 0] = ov0;
            out[OFF_OV + (n0 + j) * 3 + 1] = ov1;
            out[OFF_OV + (n0 + j) * 3 + 2] = ov2;
        }
    }
}

// ---------------------------------------------------------------------------
extern "C" void kernel_launch(void* const* d_in, const int* in_sizes, int n_in,
                              void* d_out, int out_size, void* d_ws, size_t ws_size,
                              hipStream_t stream)
{
    const float* vectors  = (const float*)d_in[0];
    const float* lengths  = (const float*)d_in[1];
    const float* node_s   = (const float*)d_in[2];
    const float* node_v   = (const float*)d_in[3];
    const float* sef      = (const float*)d_in[4];
    const int*  specie    = (const int*)d_in[5];
    const int*  senders   = (const int*)d_in[6];
    const int*  receivers = (const int*)d_in[7];
    const float* W_up_s   = (const float*)d_in[8];
    const float* b_up_s   = (const float*)d_in[9];
    const float* W_up_v   = (const float*)d_in[10];
    const float* mlp_W1   = (const float*)d_in[11];
    const float* mlp_b1   = (const float*)d_in[12];
    const float* mlp_W2   = (const float*)d_in[13];
    const float* mlp_b2   = (const float*)d_in[14];
    const float* mlp_W3   = (const float*)d_in[15];
    const float* mlp_b3   = (const float*)d_in[16];
    const float* W_dn_s   = (const float*)d_in[17];
    const float* b_dn_s   = (const float*)d_in[18];
    const float* W_dn_v   = (const float*)d_in[19];
    const float* w_sc_s   = (const float*)d_in[20];
    const float* w_sc_v   = (const float*)d_in[21];
    const float* W_pb_s   = (const float*)d_in[22];
    const float* b_pb_s   = (const float*)d_in[23];
    const float* W_pb_v   = (const float*)d_in[24];
    const float* W_r1_s   = (const float*)d_in[25];
    const float* b_r1_s   = (const float*)d_in[26];
    const float* W_r1_v   = (const float*)d_in[27];
    const float* W_r2_s   = (const float*)d_in[28];
    const float* b_r2     = (const float*)d_in[29];
    const float* W_r2_v   = (const float*)d_in[30];

    float* h_v = (float*)d_ws;                                   // N*192 f32
    ushort_t* tpx   = (ushort_t*)(h_v + (size_t)N_ * 192);       // E*192 u16
    ushort_t* hs_bf = tpx + (size_t)E_ * 192;                    // N*64 u16
    ushort_t* W1p   = hs_bf + (size_t)N_ * 64;
    ushort_t* W2p   = W1p + W1P_SZ;
    ushort_t* W3p   = W2p + W2P_SZ;
    int* cnt        = (int*)((((size_t)(W3p + W3P_SZ)) + 15) & ~(size_t)15);
    int* base       = cnt + N_;
    int* cursor     = base + N_;
    int* sorted_eid = cursor + N_;

    float* out = (float*)d_out;

    hipMemsetAsync(cnt, 0, N_ * sizeof(int), stream);

    up_kernel<<<N_ / 4, 64, 0, stream>>>(node_s, node_v, W_up_s, b_up_s, W_up_v,
                                         receivers, cnt, hs_bf, h_v);
    pack_kernel<<<256, 256, 0, stream>>>(mlp_W1, mlp_W2, mlp_W3, W1p, W2p, W3p);
    scan_kernel<<<1, 1024, 0, stream>>>(cnt, base, cursor);

    edge_mlp_kernel<<<E_ / 64, 128, 0, stream>>>(
        lengths, sef, senders, receivers,
        mlp_b1, mlp_b2, mlp_b3,
        hs_bf, W1p, W2p, W3p, cursor, sorted_eid, tpx);

    node_fused_kernel<<<N_ / 4, 64, 0, stream>>>(
        base, cnt, sorted_eid, senders, vectors,
        tpx, hs_bf, h_v, specie,
        W_dn_s, b_dn_s, W_dn_v, w_sc_s, w_sc_v,
        W_pb_s, b_pb_s, W_pb_v, W_r1_s, b_r1_s, W_r1_v,
        W_r2_s, b_r2, W_r2_v, out);
}

// Round 7
// 424.879 us; speedup vs baseline: 1.1532x; 1.1532x over previous
//
#include <hip/hip_runtime.h>

typedef short bf16x8 __attribute__((ext_vector_type(8)));
typedef float f32x4  __attribute__((ext_vector_type(4)));
typedef unsigned short ushort_t;

__device__ __forceinline__ float silu(float x) {
    float t = __expf(-x);
    return x * __builtin_amdgcn_rcpf(1.f + t);
}

__device__ __forceinline__ ushort_t f2bs(float x) {
    union { float f; unsigned int u; } v; v.f = x;
    unsigned int r = v.u + 0x7FFF + ((v.u >> 16) & 1);
    return (ushort_t)(r >> 16);
}
__device__ __forceinline__ ushort_t f2bs_t(float x) {
    union { float f; unsigned int u; } v; v.f = x;
    return (ushort_t)(v.u >> 16);
}
__device__ __forceinline__ float bs2f(ushort_t x) {
    union { unsigned int u; float f; } v; v.u = ((unsigned int)x) << 16; return v.f;
}

constexpr int N_   = 16000;
constexpr int E_   = 256000;
constexpr int Fd   = 64;

constexpr float SQ3f    = 1.7320508075688772f;
constexpr float INV_SQ3 = 0.5773502691896258f;
constexpr float INV_SQ2 = 0.7071067811865476f;
constexpr float INV_AVG = 0.0625f;

constexpr int OFF_OS = 0;
constexpr int OFF_OV = N_;
constexpr int OFF_PS = OFF_OV + 3 * N_;
constexpr int OFF_PV = OFF_PS + N_ * Fd;

constexpr int W1P_SZ = 6 * 8 * 512;
constexpr int W2P_SZ = 4 * 8 * 512;
constexpr int W3P_SZ = 4 * 12 * 512;

// ---------------------------------------------------------------------------
// pack weights fp32 -> bf16 MFMA B-fragment order
// ---------------------------------------------------------------------------
__global__ __launch_bounds__(256) void pack_kernel(
    const float* __restrict__ W1, const float* __restrict__ W2,
    const float* __restrict__ W3,
    ushort_t* __restrict__ W1p, ushort_t* __restrict__ W2p,
    ushort_t* __restrict__ W3p)
{
    int idx = blockIdx.x * 256 + threadIdx.x;
    if (idx < W1P_SZ) {
        int j = idx & 7, lane = (idx >> 3) & 63, tile = idx >> 9;
        int c = tile >> 3, t = tile & 7;
        int k = c * 32 + (lane >> 4) * 8 + j;
        int n = t * 16 + (lane & 15);
        W1p[idx] = f2bs(k < 161 ? W1[k * 128 + n] : 0.f);
    } else if (idx < W1P_SZ + W2P_SZ) {
        int q = idx - W1P_SZ;
        int j = q & 7, lane = (q >> 3) & 63, tile = q >> 9;
        int c = tile >> 3, t = tile & 7;
        int k = c * 32 + (lane >> 4) * 8 + j;
        int n = t * 16 + (lane & 15);
        W2p[q] = f2bs(W2[k * 128 + n]);
    } else {
        int q = idx - W1P_SZ - W2P_SZ;
        int j = q & 7, lane = (q >> 3) & 63, tile = q >> 9;
        int c = tile / 12, t = tile % 12;
        int k = c * 32 + (lane >> 4) * 8 + j;
        int n = t * 16 + (lane & 15);
        W3p[q] = f2bs(W3[k * 192 + n]);
    }
}

// ---------------------------------------------------------------------------
// Kernel 1: up-projection, 4 nodes/block. h_s bf16; h_v fp32 SoA.
// Fused receiver-count (64 edges/block).
// ---------------------------------------------------------------------------
__global__ __launch_bounds__(64, 4) void up_kernel(
    const float* __restrict__ node_s, const float* __restrict__ node_v,
    const float* __restrict__ W_up_s, const float* __restrict__ b_up_s,
    const float* __restrict__ W_up_v,
    const int* __restrict__ receivers, int* __restrict__ cnt,
    ushort_t* __restrict__ hs_bf, float* __restrict__ h_v)
{
    __shared__ float ns[4][64];
    __shared__ float nv[4][64][3];
    const int n0 = blockIdx.x * 4;
    const int g  = threadIdx.x;

    {
        int e = blockIdx.x * 64 + g;
        atomicAdd(&cnt[receivers[e]], 1);
    }

    #pragma unroll
    for (int j = 0; j < 4; j++) ns[j][g] = node_s[(n0 + j) * 64 + g];
    for (int idx = g; idx < 4 * 192; idx += 64) {
        int j = idx / 192, r = idx - j * 192;
        nv[j][r / 3][r % 3] = node_v[(size_t)n0 * 192 + idx];
    }
    __syncthreads();

    float as[4], a0[4], a1[4], a2[4];
    float bb = b_up_s[g];
    #pragma unroll
    for (int j = 0; j < 4; j++) { as[j] = bb; a0[j] = a1[j] = a2[j] = 0.f; }
    #pragma unroll 4
    for (int f = 0; f < 64; f++) {
        float wss = W_up_s[f * 64 + g];
        float wv  = W_up_v[f * 64 + g];
        #pragma unroll
        for (int j = 0; j < 4; j++) {
            as[j] += ns[j][f] * wss;
            a0[j] += nv[j][f][0] * wv;
            a1[j] += nv[j][f][1] * wv;
            a2[j] += nv[j][f][2] * wv;
        }
    }
    #pragma unroll
    for (int j = 0; j < 4; j++) {
        hs_bf[(n0 + j) * 64 + g] = f2bs(as[j]);
        h_v[(n0 + j) * 192 + 0 * 64 + g] = a0[j];
        h_v[(n0 + j) * 192 + 1 * 64 + g] = a1[j];
        h_v[(n0 + j) * 192 + 2 * 64 + g] = a2[j];
    }
}

// ---------------------------------------------------------------------------
// CSR scan
// ---------------------------------------------------------------------------
__global__ __launch_bounds__(1024) void scan_kernel(
    const int* __restrict__ cnt, int* __restrict__ base, int* __restrict__ cursor)
{
    __shared__ int part[1024];
    const int t = threadIdx.x;
    int v[16];
    int s = 0;
    if (t < 1000) {
        const int4* c4 = (const int4*)(cnt + t * 16);
        #pragma unroll
        for (int q = 0; q < 4; q++) {
            int4 w = c4[q];
            v[q * 4 + 0] = w.x; v[q * 4 + 1] = w.y;
            v[q * 4 + 2] = w.z; v[q * 4 + 3] = w.w;
            s += w.x + w.y + w.z + w.w;
        }
    }
    part[t] = s;
    __syncthreads();
    for (int off = 1; off < 1024; off <<= 1) {
        int u = (t >= off) ? part[t - off] : 0;
        __syncthreads();
        part[t] += u;
        __syncthreads();
    }
    if (t < 1000) {
        int run = part[t] - s;
        int b[16];
        #pragma unroll
        for (int i = 0; i < 16; i++) { b[i] = run; run += v[i]; }
        int4* bb = (int4*)(base + t * 16);
        int4* cc = (int4*)(cursor + t * 16);
        #pragma unroll
        for (int q = 0; q < 4; q++) {
            int4 w = { b[q * 4], b[q * 4 + 1], b[q * 4 + 2], b[q * 4 + 3] };
            bb[q] = w;
            cc[q] = w;
        }
    }
}

// ---------------------------------------------------------------------------
// Kernel 2: MFMA edge MLP, M=32 edges/wave. GEMM3 split in 2 halves to cut
// peak VGPR. 128 threads = 2 waves, 64 edges/block. Fused CSR scatter.
// ---------------------------------------------------------------------------
__global__ __launch_bounds__(128, 3) void edge_mlp_kernel(
    const float* __restrict__ lengths, const float* __restrict__ sef,
    const int* __restrict__ senders, const int* __restrict__ receivers,
    const float* __restrict__ b1f, const float* __restrict__ b2f,
    const float* __restrict__ b3f,
    const ushort_t* __restrict__ hs_bf,
    const ushort_t* __restrict__ W1p, const ushort_t* __restrict__ W2p,
    const ushort_t* __restrict__ W3p,
    int* __restrict__ cursor, int* __restrict__ sorted_eid,
    ushort_t* __restrict__ tpx)
{
    __shared__ ushort_t Hs[64 * 136];

    const int tid  = threadIdx.x;
    const int wave = tid >> 6, lane = tid & 63;
    const int quad = lane >> 4, l4 = lane & 15;
    const int ebase = blockIdx.x * 64 + wave * 32;
    const int me0   = ebase + l4;
    const int me1   = ebase + 16 + l4;
    const int hrow  = wave * 32;

    if (tid < 64) {
        int e = blockIdx.x * 64 + tid;
        int p = atomicAdd(&cursor[receivers[e]], 1);
        sorted_eid[p] = e;
    }

    const int snd0 = senders[me0], rcv0 = receivers[me0];
    const int snd1 = senders[me1], rcv1 = receivers[me1];

    bf16x8 a0[6], a1[6];
    a0[0] = *(const bf16x8*)(hs_bf + snd0 * 64 + quad * 8);
    a0[1] = *(const bf16x8*)(hs_bf + snd0 * 64 + 32 + quad * 8);
    a0[2] = *(const bf16x8*)(hs_bf + rcv0 * 64 + quad * 8);
    a0[3] = *(const bf16x8*)(hs_bf + rcv0 * 64 + 32 + quad * 8);
    a1[0] = *(const bf16x8*)(hs_bf + snd1 * 64 + quad * 8);
    a1[1] = *(const bf16x8*)(hs_bf + snd1 * 64 + 32 + quad * 8);
    a1[2] = *(const bf16x8*)(hs_bf + rcv1 * 64 + quad * 8);
    a1[3] = *(const bf16x8*)(hs_bf + rcv1 * 64 + 32 + quad * 8);
    {
        const float4 s0 = *(const float4*)(sef + (size_t)me0 * 32 + quad * 8);
        const float4 s1 = *(const float4*)(sef + (size_t)me0 * 32 + quad * 8 + 4);
        bf16x8 t;
        t[0] = (short)f2bs(s0.x); t[1] = (short)f2bs(s0.y);
        t[2] = (short)f2bs(s0.z); t[3] = (short)f2bs(s0.w);
        t[4] = (short)f2bs(s1.x); t[5] = (short)f2bs(s1.y);
        t[6] = (short)f2bs(s1.z); t[7] = (short)f2bs(s1.w);
        a0[4] = t;
        const float4 u0 = *(const float4*)(sef + (size_t)me1 * 32 + quad * 8);
        const float4 u1 = *(const float4*)(sef + (size_t)me1 * 32 + quad * 8 + 4);
        t[0] = (short)f2bs(u0.x); t[1] = (short)f2bs(u0.y);
        t[2] = (short)f2bs(u0.z); t[3] = (short)f2bs(u0.w);
        t[4] = (short)f2bs(u1.x); t[5] = (short)f2bs(u1.y);
        t[6] = (short)f2bs(u1.z); t[7] = (short)f2bs(u1.w);
        a1[4] = t;
    }
    {
        bf16x8 t = {0,0,0,0,0,0,0,0};
        bf16x8 u = {0,0,0,0,0,0,0,0};
        if (quad == 0) { t[0] = (short)f2bs(lengths[me0]); u[0] = (short)f2bs(lengths[me1]); }
        a0[5] = t; a1[5] = u;
    }

    const bf16x8* B1 = (const bf16x8*)W1p;
    const bf16x8* B2 = (const bf16x8*)W2p;
    const bf16x8* B3 = (const bf16x8*)W3p;

    // GEMM1
    f32x4 accA[8], accB[8];
    #pragma unroll
    for (int t = 0; t < 8; t++) { accA[t] = (f32x4){0,0,0,0}; accB[t] = (f32x4){0,0,0,0}; }
    #pragma unroll
    for (int c = 0; c < 6; c++) {
        #pragma unroll
        for (int t = 0; t < 8; t++) {
            bf16x8 b = B1[(c * 8 + t) * 64 + lane];
            accA[t] = __builtin_amdgcn_mfma_f32_16x16x32_bf16(a0[c], b, accA[t], 0, 0, 0);
            accB[t] = __builtin_amdgcn_mfma_f32_16x16x32_bf16(a1[c], b, accB[t], 0, 0, 0);
        }
    }
    #pragma unroll
    for (int t = 0; t < 8; t++) {
        float bb = b1f[t * 16 + l4];
        #pragma unroll
        for (int r = 0; r < 4; r++) {
            Hs[(hrow + quad * 4 + r) * 136 + t * 16 + l4]      = f2bs_t(silu(accA[t][r] + bb));
            Hs[(hrow + 16 + quad * 4 + r) * 136 + t * 16 + l4] = f2bs_t(silu(accB[t][r] + bb));
        }
    }

    // GEMM2
    #pragma unroll
    for (int t = 0; t < 8; t++) { accA[t] = (f32x4){0,0,0,0}; accB[t] = (f32x4){0,0,0,0}; }
    #pragma unroll
    for (int c = 0; c < 4; c++) {
        bf16x8 af0 = *(const bf16x8*)(&Hs[(hrow + l4) * 136 + c * 32 + quad * 8]);
        bf16x8 af1 = *(const bf16x8*)(&Hs[(hrow + 16 + l4) * 136 + c * 32 + quad * 8]);
        #pragma unroll
        for (int t = 0; t < 8; t++) {
            bf16x8 b = B2[(c * 8 + t) * 64 + lane];
            accA[t] = __builtin_amdgcn_mfma_f32_16x16x32_bf16(af0, b, accA[t], 0, 0, 0);
            accB[t] = __builtin_amdgcn_mfma_f32_16x16x32_bf16(af1, b, accB[t], 0, 0, 0);
        }
    }
    #pragma unroll
    for (int t = 0; t < 8; t++) {
        float bb = b2f[t * 16 + l4];
        #pragma unroll
        for (int r = 0; r < 4; r++) {
            Hs[(hrow + quad * 4 + r) * 136 + t * 16 + l4]      = f2bs_t(silu(accA[t][r] + bb));
            Hs[(hrow + 16 + quad * 4 + r) * 136 + t * 16 + l4] = f2bs_t(silu(accB[t][r] + bb));
        }
    }

    // GEMM3 in two halves of 6 tiles (halves peak acc3 registers)
    #pragma unroll
    for (int half = 0; half < 2; half++) {
        f32x4 acc3A[6], acc3B[6];
        #pragma unroll
        for (int t = 0; t < 6; t++) { acc3A[t] = (f32x4){0,0,0,0}; acc3B[t] = (f32x4){0,0,0,0}; }
        #pragma unroll
        for (int c = 0; c < 4; c++) {
            bf16x8 af0 = *(const bf16x8*)(&Hs[(hrow + l4) * 136 + c * 32 + quad * 8]);
            bf16x8 af1 = *(const bf16x8*)(&Hs[(hrow + 16 + l4) * 136 + c * 32 + quad * 8]);
            #pragma unroll
            for (int t = 0; t < 6; t++) {
                bf16x8 b = B3[(c * 12 + half * 6 + t) * 64 + lane];
                acc3A[t] = __builtin_amdgcn_mfma_f32_16x16x32_bf16(af0, b, acc3A[t], 0, 0, 0);
                acc3B[t] = __builtin_amdgcn_mfma_f32_16x16x32_bf16(af1, b, acc3B[t], 0, 0, 0);
            }
        }
        #pragma unroll
        for (int t = 0; t < 6; t++) {
            int tt = half * 6 + t;
            float bb = b3f[tt * 16 + l4];
            #pragma unroll
            for (int r = 0; r < 4; r++) {
                tpx[(size_t)(ebase + quad * 4 + r) * 192 + tt * 16 + l4]      = f2bs(acc3A[t][r] + bb);
                tpx[(size_t)(ebase + 16 + quad * 4 + r) * 192 + tt * 16 + l4] = f2bs(acc3B[t][r] + bb);
            }
        }
    }
}

// ---------------------------------------------------------------------------
// Kernel 3: CSR aggregation + node tail. 256 threads = 4 waves; wave w owns
// node blockIdx*4+w end-to-end (restores 16000-wave parallelism). No
// __syncthreads: each wave's LDS region is private, wave ordering suffices.
// Cross-wave tail-weight reuse comes via L1 (4 waves stream same weights).
// ---------------------------------------------------------------------------
__global__ __launch_bounds__(256, 2) void node_fused_kernel(
    const int* __restrict__ base, const int* __restrict__ cnt,
    const int* __restrict__ sorted_eid, const int* __restrict__ senders,
    const float* __restrict__ vectors,
    const ushort_t* __restrict__ tpx,
    const ushort_t* __restrict__ hs_bf, const float* __restrict__ h_v,
    const int* __restrict__ specie,
    const float* __restrict__ W_dn_s, const float* __restrict__ b_dn_s,
    const float* __restrict__ W_dn_v,
    const float* __restrict__ w_sc_s, const float* __restrict__ w_sc_v,
    const float* __restrict__ W_pb_s, const float* __restrict__ b_pb_s,
    const float* __restrict__ W_pb_v,
    const float* __restrict__ W_r1_s, const float* __restrict__ b_r1_s,
    const float* __restrict__ W_r1_v,
    const float* __restrict__ W_r2_s, const float* __restrict__ b_r2,
    const float* __restrict__ W_r2_v,
    float* __restrict__ out)
{
    __shared__ float as_l[4][64];
    __shared__ float av_l[4][128][3];
    __shared__ float scs[4][64];
    __shared__ float scv[4][64][3];
    __shared__ float ps_[4][64];
    __shared__ float pv_[4][64][3];
    __shared__ int   eids[4][64];

    const int tid = threadIdx.x;
    const int w   = tid >> 6;
    const int g   = tid & 63;
    const int n   = blockIdx.x * 4 + w;

    // ---- per-wave CSR aggregation ----
    const int b = base[n];
    const int c = cnt[n];
    float accS = 0.f;
    float a10 = 0.f, a11 = 0.f, a12 = 0.f;
    float a20 = 0.f, a21 = 0.f, a22 = 0.f;

    for (int done = 0; done < c; done += 64) {
        int m = min(64, c - done);
        if (g < m) eids[w][g] = sorted_eid[b + done + g];
        for (int i = 0; i < m; i++) {
            const int e  = eids[w][i];
            const int se = senders[e];
            const float ev0 = SQ3f * vectors[e * 3 + 0];
            const float ev1 = SQ3f * vectors[e * 3 + 1];
            const float ev2 = SQ3f * vectors[e * 3 + 2];
            const float mv0 = h_v[(size_t)se * 192 + 0 * 64 + g];
            const float mv1 = h_v[(size_t)se * 192 + 1 * 64 + g];
            const float mv2 = h_v[(size_t)se * 192 + 2 * 64 + g];
            const float m_s = bs2f(hs_bf[se * 64 + g]);
            const ushort_t* mrow = tpx + (size_t)e * 192;
            const float c0 = bs2f(mrow[g]);
            const float c1 = bs2f(mrow[64 + g]);
            const float c2 = bs2f(mrow[128 + g]);

            float dot = mv0 * ev0 + mv1 * ev1 + mv2 * ev2;
            accS += dot * c0;
            float k1 = m_s * c1;
            a10 += k1 * ev0; a11 += k1 * ev1; a12 += k1 * ev2;
            a20 += (mv1 * ev2 - mv2 * ev1) * c2;
            a21 += (mv2 * ev0 - mv0 * ev2) * c2;
            a22 += (mv0 * ev1 - mv1 * ev0) * c2;
        }
    }
    as_l[w][g] = accS * (INV_SQ3 * INV_AVG);
    av_l[w][g][0] = a10 * INV_AVG;
    av_l[w][g][1] = a11 * INV_AVG;
    av_l[w][g][2] = a12 * INV_AVG;
    av_l[w][64 + g][0] = a20 * (INV_SQ2 * INV_AVG);
    av_l[w][64 + g][1] = a21 * (INV_SQ2 * INV_AVG);
    av_l[w][64 + g][2] = a22 * (INV_SQ2 * INV_AVG);
    // same wave reads its own LDS region next — no barrier needed

    // ---- node tail (per-wave) ----
    float f_s = b_dn_s[g];
    #pragma unroll 8
    for (int f = 0; f < 64; f++) f_s += as_l[w][f] * W_dn_s[f * 64 + g];
    float fv0 = 0.f, fv1 = 0.f, fv2 = 0.f;
    #pragma unroll 8
    for (int f = 0; f < 128; f++) {
        float wt = W_dn_v[f * 64 + g];
        fv0 += av_l[w][f][0] * wt;
        fv1 += av_l[w][f][1] * wt;
        fv2 += av_l[w][f][2] * wt;
    }

    float vv = (fv0 * fv0 + fv1 * fv1 + fv2 * fv2) * INV_SQ3;
    int sp = specie[n];
    float ws0 = w_sc_s[sp * 192 + 0 * 64 + g];
    float ws1 = w_sc_s[sp * 192 + 1 * 64 + g];
    float ws2 = w_sc_s[sp * 192 + 2 * 64 + g];
    float wv0 = w_sc_v[sp * 128 + 0 * 64 + g];
    float wv1 = w_sc_v[sp * 128 + 1 * 64 + g];
    float sc_s = ws0 * f_s + ws1 * f_s * f_s + ws2 * vv;
    float kv = wv0 + wv1 * f_s;
    scs[w][g] = sc_s;
    scv[w][g][0] = kv * fv0;
    scv[w][g][1] = kv * fv1;
    scv[w][g][2] = kv * fv2;

    float p_s = b_pb_s[g];
    float pv0 = 0.f, pv1 = 0.f, pv2 = 0.f;
    #pragma unroll 8
    for (int f = 0; f < 64; f++) {
        float wps = W_pb_s[f * 64 + g];
        p_s += scs[w][f] * wps;
        float wpv = W_pb_v[f * 64 + g];
        pv0 += scv[w][f][0] * wpv;
        pv1 += scv[w][f][1] * wpv;
        pv2 += scv[w][f][2] * wpv;
    }
    ps_[w][g] = p_s;
    pv_[w][g][0] = pv0; pv_[w][g][1] = pv1; pv_[w][g][2] = pv2;

    out[OFF_PS + n * 64 + g] = p_s;
    out[OFF_PV + (size_t)n * 192 + g * 3 + 0] = pv0;
    out[OFF_PV + (size_t)n * 192 + g * 3 + 1] = pv1;
    out[OFF_PV + (size_t)n * 192 + g * 3 + 2] = pv2;

    float r0 = b_r1_s[g];
    float r1 = b_r1_s[g + 64];
    float rv0 = 0.f, rv1 = 0.f, rv2 = 0.f;
    #pragma unroll 8
    for (int f = 0; f < 64; f++) {
        float p = ps_[w][f];
        r0 += p * W_r1_s[f * 128 + g];
        r1 += p * W_r1_s[f * 128 + g + 64];
        float wrv = W_r1_v[f * 64 + g];
        rv0 += pv_[w][f][0] * wrv;
        rv1 += pv_[w][f][1] * wrv;
        rv2 += pv_[w][f][2] * wrv;
    }
    float act  = silu(r0);
    float gate = silu(r1);
    float o_s = act * W_r2_s[g];
    float wr2v = W_r2_v[g];
    float ov0 = gate * rv0 * wr2v;
    float ov1 = gate * rv1 * wr2v;
    float ov2 = gate * rv2 * wr2v;

    #pragma unroll
    for (int off = 32; off > 0; off >>= 1) {
        o_s += __shfl_down(o_s, off);
        ov0 += __shfl_down(ov0, off);
        ov1 += __shfl_down(ov1, off);
        ov2 += __shfl_down(ov2, off);
    }
    if (g == 0) {
        out[OFF_OS + n] = o_s + b_r2[0];
        out[OFF_OV + n * 3 + 0] = ov0;
        out[OFF_OV + n * 3 + 1] = ov1;
        out[OFF_OV + n * 3 + 2] = ov2;
    }
}

// ---------------------------------------------------------------------------
extern "C" void kernel_launch(void* const* d_in, const int* in_sizes, int n_in,
                              void* d_out, int out_size, void* d_ws, size_t ws_size,
                              hipStream_t stream)
{
    const float* vectors  = (const float*)d_in[0];
    const float* lengths  = (const float*)d_in[1];
    const float* node_s   = (const float*)d_in[2];
    const float* node_v   = (const float*)d_in[3];
    const float* sef      = (const float*)d_in[4];
    const int*  specie    = (const int*)d_in[5];
    const int*  senders   = (const int*)d_in[6];
    const int*  receivers = (const int*)d_in[7];
    const float* W_up_s   = (const float*)d_in[8];
    const float* b_up_s   = (const float*)d_in[9];
    const float* W_up_v   = (const float*)d_in[10];
    const float* mlp_W1   = (const float*)d_in[11];
    const float* mlp_b1   = (const float*)d_in[12];
    const float* mlp_W2   = (const float*)d_in[13];
    const float* mlp_b2   = (const float*)d_in[14];
    const float* mlp_W3   = (const float*)d_in[15];
    const float* mlp_b3   = (const float*)d_in[16];
    const float* W_dn_s   = (const float*)d_in[17];
    const float* b_dn_s   = (const float*)d_in[18];
    const float* W_dn_v   = (const float*)d_in[19];
    const float* w_sc_s   = (const float*)d_in[20];
    const float* w_sc_v   = (const float*)d_in[21];
    const float* W_pb_s   = (const float*)d_in[22];
    const float* b_pb_s   = (const float*)d_in[23];
    const float* W_pb_v   = (const float*)d_in[24];
    const float* W_r1_s   = (const float*)d_in[25];
    const float* b_r1_s   = (const float*)d_in[26];
    const float* W_r1_v   = (const float*)d_in[27];
    const float* W_r2_s   = (const float*)d_in[28];
    const float* b_r2     = (const float*)d_in[29];
    const float* W_r2_v   = (const float*)d_in[30];

    float* h_v = (float*)d_ws;                                   // N*192 f32
    ushort_t* tpx   = (ushort_t*)(h_v + (size_t)N_ * 192);       // E*192 u16
    ushort_t* hs_bf = tpx + (size_t)E_ * 192;                    // N*64 u16
    ushort_t* W1p   = hs_bf + (size_t)N_ * 64;
    ushort_t* W2p   = W1p + W1P_SZ;
    ushort_t* W3p   = W2p + W2P_SZ;
    int* cnt        = (int*)((((size_t)(W3p + W3P_SZ)) + 15) & ~(size_t)15);
    int* base       = cnt + N_;
    int* cursor     = base + N_;
    int* sorted_eid = cursor + N_;

    float* out = (float*)d_out;

    hipMemsetAsync(cnt, 0, N_ * sizeof(int), stream);

    up_kernel<<<N_ / 4, 64, 0, stream>>>(node_s, node_v, W_up_s, b_up_s, W_up_v,
                                         receivers, cnt, hs_bf, h_v);
    pack_kernel<<<256, 256, 0, stream>>>(mlp_W1, mlp_W2, mlp_W3, W1p, W2p, W3p);
    scan_kernel<<<1, 1024, 0, stream>>>(cnt, base, cursor);

    edge_mlp_kernel<<<E_ / 64, 128, 0, stream>>>(
        lengths, sef, senders, receivers,
        mlp_b1, mlp_b2, mlp_b3,
        hs_bf, W1p, W2p, W3p, cursor, sorted_eid, tpx);

    node_fused_kernel<<<N_ / 4, 256, 0, stream>>>(
        base, cnt, sorted_eid, senders, vectors,
        tpx, hs_bf, h_v, specie,
        W_dn_s, b_dn_s, W_dn_v, w_sc_s, w_sc_v,
        W_pb_s, b_pb_s, W_pb_v, W_r1_s, b_r1_s, W_r1_v,
        W_r2_s, b_r2, W_r2_v, out);
}

// Round 8
// 364.373 us; speedup vs baseline: 1.3447x; 1.1661x over previous
//
#include <hip/hip_runtime.h>

typedef short bf16x8 __attribute__((ext_vector_type(8)));
typedef float f32x4  __attribute__((ext_vector_type(4)));
typedef unsigned short ushort_t;

__device__ __forceinline__ float silu(float x) {
    float t = __expf(-x);
    return x * __builtin_amdgcn_rcpf(1.f + t);
}

__device__ __forceinline__ ushort_t f2bs(float x) {
    union { float f; unsigned int u; } v; v.f = x;
    unsigned int r = v.u + 0x7FFF + ((v.u >> 16) & 1);
    return (ushort_t)(r >> 16);
}
__device__ __forceinline__ ushort_t f2bs_t(float x) {
    union { float f; unsigned int u; } v; v.f = x;
    return (ushort_t)(v.u >> 16);
}
__device__ __forceinline__ float bs2f(ushort_t x) {
    union { unsigned int u; float f; } v; v.u = ((unsigned int)x) << 16; return v.f;
}

constexpr int N_   = 16000;
constexpr int E_   = 256000;
constexpr int Fd   = 64;

constexpr float SQ3f    = 1.7320508075688772f;
constexpr float INV_SQ3 = 0.5773502691896258f;
constexpr float INV_SQ2 = 0.7071067811865476f;
constexpr float INV_AVG = 0.0625f;

constexpr int OFF_OS = 0;
constexpr int OFF_OV = N_;
constexpr int OFF_PS = OFF_OV + 3 * N_;
constexpr int OFF_PV = OFF_PS + N_ * Fd;

constexpr int W1P_SZ = 6 * 8 * 512;
constexpr int W2P_SZ = 4 * 8 * 512;
constexpr int W3P_SZ = 4 * 12 * 512;

// ---------------------------------------------------------------------------
// pack weights fp32 -> bf16 MFMA B-fragment order
// ---------------------------------------------------------------------------
__global__ __launch_bounds__(256) void pack_kernel(
    const float* __restrict__ W1, const float* __restrict__ W2,
    const float* __restrict__ W3,
    ushort_t* __restrict__ W1p, ushort_t* __restrict__ W2p,
    ushort_t* __restrict__ W3p)
{
    int idx = blockIdx.x * 256 + threadIdx.x;
    if (idx < W1P_SZ) {
        int j = idx & 7, lane = (idx >> 3) & 63, tile = idx >> 9;
        int c = tile >> 3, t = tile & 7;
        int k = c * 32 + (lane >> 4) * 8 + j;
        int n = t * 16 + (lane & 15);
        W1p[idx] = f2bs(k < 161 ? W1[k * 128 + n] : 0.f);
    } else if (idx < W1P_SZ + W2P_SZ) {
        int q = idx - W1P_SZ;
        int j = q & 7, lane = (q >> 3) & 63, tile = q >> 9;
        int c = tile >> 3, t = tile & 7;
        int k = c * 32 + (lane >> 4) * 8 + j;
        int n = t * 16 + (lane & 15);
        W2p[q] = f2bs(W2[k * 128 + n]);
    } else {
        int q = idx - W1P_SZ - W2P_SZ;
        int j = q & 7, lane = (q >> 3) & 63, tile = q >> 9;
        int c = tile / 12, t = tile % 12;
        int k = c * 32 + (lane >> 4) * 8 + j;
        int n = t * 16 + (lane & 15);
        W3p[q] = f2bs(W3[k * 192 + n]);
    }
}

// ---------------------------------------------------------------------------
// Kernel 1: up-projection, 4 nodes/block. h_s bf16; h_v fp32 SoA.
// Fused receiver-count (64 edges/block).
// ---------------------------------------------------------------------------
__global__ __launch_bounds__(64, 4) void up_kernel(
    const float* __restrict__ node_s, const float* __restrict__ node_v,
    const float* __restrict__ W_up_s, const float* __restrict__ b_up_s,
    const float* __restrict__ W_up_v,
    const int* __restrict__ receivers, int* __restrict__ cnt,
    ushort_t* __restrict__ hs_bf, float* __restrict__ h_v)
{
    __shared__ float ns[4][64];
    __shared__ float nv[4][64][3];
    const int n0 = blockIdx.x * 4;
    const int g  = threadIdx.x;

    {
        int e = blockIdx.x * 64 + g;
        atomicAdd(&cnt[receivers[e]], 1);
    }

    #pragma unroll
    for (int j = 0; j < 4; j++) ns[j][g] = node_s[(n0 + j) * 64 + g];
    for (int idx = g; idx < 4 * 192; idx += 64) {
        int j = idx / 192, r = idx - j * 192;
        nv[j][r / 3][r % 3] = node_v[(size_t)n0 * 192 + idx];
    }
    __syncthreads();

    float as[4], a0[4], a1[4], a2[4];
    float bb = b_up_s[g];
    #pragma unroll
    for (int j = 0; j < 4; j++) { as[j] = bb; a0[j] = a1[j] = a2[j] = 0.f; }
    #pragma unroll 4
    for (int f = 0; f < 64; f++) {
        float wss = W_up_s[f * 64 + g];
        float wv  = W_up_v[f * 64 + g];
        #pragma unroll
        for (int j = 0; j < 4; j++) {
            as[j] += ns[j][f] * wss;
            a0[j] += nv[j][f][0] * wv;
            a1[j] += nv[j][f][1] * wv;
            a2[j] += nv[j][f][2] * wv;
        }
    }
    #pragma unroll
    for (int j = 0; j < 4; j++) {
        hs_bf[(n0 + j) * 64 + g] = f2bs(as[j]);
        h_v[(n0 + j) * 192 + 0 * 64 + g] = a0[j];
        h_v[(n0 + j) * 192 + 1 * 64 + g] = a1[j];
        h_v[(n0 + j) * 192 + 2 * 64 + g] = a2[j];
    }
}

// ---------------------------------------------------------------------------
// CSR scan
// ---------------------------------------------------------------------------
__global__ __launch_bounds__(1024) void scan_kernel(
    const int* __restrict__ cnt, int* __restrict__ base, int* __restrict__ cursor)
{
    __shared__ int part[1024];
    const int t = threadIdx.x;
    int v[16];
    int s = 0;
    if (t < 1000) {
        const int4* c4 = (const int4*)(cnt + t * 16);
        #pragma unroll
        for (int q = 0; q < 4; q++) {
            int4 w = c4[q];
            v[q * 4 + 0] = w.x; v[q * 4 + 1] = w.y;
            v[q * 4 + 2] = w.z; v[q * 4 + 3] = w.w;
            s += w.x + w.y + w.z + w.w;
        }
    }
    part[t] = s;
    __syncthreads();
    for (int off = 1; off < 1024; off <<= 1) {
        int u = (t >= off) ? part[t - off] : 0;
        __syncthreads();
        part[t] += u;
        __syncthreads();
    }
    if (t < 1000) {
        int run = part[t] - s;
        int b[16];
        #pragma unroll
        for (int i = 0; i < 16; i++) { b[i] = run; run += v[i]; }
        int4* bb = (int4*)(base + t * 16);
        int4* cc = (int4*)(cursor + t * 16);
        #pragma unroll
        for (int q = 0; q < 4; q++) {
            int4 w = { b[q * 4], b[q * 4 + 1], b[q * 4 + 2], b[q * 4 + 3] };
            bb[q] = w;
            cc[q] = w;
        }
    }
}

// ---------------------------------------------------------------------------
// Kernel 2: cooperative MFMA edge MLP. 256 thr = 4 waves share a 64-edge
// tile; waves split the N dimension (2/8 tiles GEMM1-2, 3/12 GEMM3), so each
// wave issues only ~32 global weight loads (was 128). A staged in LDS;
// H2 reuses the A region. 3 barriers. Fused CSR scatter.
// ---------------------------------------------------------------------------
__global__ __launch_bounds__(256, 3) void edge_mlp_kernel(
    const float* __restrict__ lengths, const float* __restrict__ sef,
    const int* __restrict__ senders, const int* __restrict__ receivers,
    const float* __restrict__ b1f, const float* __restrict__ b2f,
    const float* __restrict__ b3f,
    const ushort_t* __restrict__ hs_bf,
    const ushort_t* __restrict__ W1p, const ushort_t* __restrict__ W2p,
    const ushort_t* __restrict__ W3p,
    int* __restrict__ cursor, int* __restrict__ sorted_eid,
    ushort_t* __restrict__ tpx)
{
    __shared__ ushort_t Als[64 * 200];  // A (GEMM1), then H2 (stride 136)
    __shared__ ushort_t Hs[64 * 136];   // H1

    const int tid  = threadIdx.x;
    const int wave = tid >> 6, lane = tid & 63;
    const int quad = lane >> 4, l4 = lane & 15;
    const int e0   = blockIdx.x * 64;

    if (tid < 64) {
        int e = e0 + tid;
        int p = atomicAdd(&cursor[receivers[e]], 1);
        sorted_eid[p] = e;
    }

    // ---- stage mlp_in rows: 64 edges x 192 bf16 (pad 200), 24 chunks ----
    {
        const int e  = tid & 63;
        const int ge = e0 + e;
        const int snd = senders[ge];
        const int rcv = receivers[ge];
        for (int c = tid >> 6; c < 24; c += 4) {
            bf16x8 v;
            if (c < 8) {
                v = *(const bf16x8*)(hs_bf + snd * 64 + c * 8);
            } else if (c < 16) {
                v = *(const bf16x8*)(hs_bf + rcv * 64 + (c - 8) * 8);
            } else if (c < 20) {
                const float4 s0 = *(const float4*)(sef + (size_t)ge * 32 + (c - 16) * 8);
                const float4 s1 = *(const float4*)(sef + (size_t)ge * 32 + (c - 16) * 8 + 4);
                v[0] = (short)f2bs(s0.x); v[1] = (short)f2bs(s0.y);
                v[2] = (short)f2bs(s0.z); v[3] = (short)f2bs(s0.w);
                v[4] = (short)f2bs(s1.x); v[5] = (short)f2bs(s1.y);
                v[6] = (short)f2bs(s1.z); v[7] = (short)f2bs(s1.w);
            } else if (c == 20) {
                v = (bf16x8){0,0,0,0,0,0,0,0};
                v[0] = (short)f2bs(lengths[ge]);
            } else {
                v = (bf16x8){0,0,0,0,0,0,0,0};
            }
            *(bf16x8*)(&Als[e * 200 + c * 8]) = v;
        }
    }
    __syncthreads();

    const bf16x8* B1 = (const bf16x8*)W1p;
    const bf16x8* B2 = (const bf16x8*)W2p;
    const bf16x8* B3 = (const bf16x8*)W3p;

    // ---- GEMM1: wave owns N-tiles {2w, 2w+1}; M = 64 edges (4 m-tiles) ----
    {
        f32x4 acc[2][4];
        #pragma unroll
        for (int ti = 0; ti < 2; ti++)
            #pragma unroll
            for (int m = 0; m < 4; m++) acc[ti][m] = (f32x4){0,0,0,0};
        #pragma unroll
        for (int c = 0; c < 6; c++) {
            bf16x8 b0 = B1[(c * 8 + wave * 2 + 0) * 64 + lane];
            bf16x8 b1 = B1[(c * 8 + wave * 2 + 1) * 64 + lane];
            #pragma unroll
            for (int m = 0; m < 4; m++) {
                bf16x8 a = *(const bf16x8*)(&Als[(m * 16 + l4) * 200 + c * 32 + quad * 8]);
                acc[0][m] = __builtin_amdgcn_mfma_f32_16x16x32_bf16(a, b0, acc[0][m], 0, 0, 0);
                acc[1][m] = __builtin_amdgcn_mfma_f32_16x16x32_bf16(a, b1, acc[1][m], 0, 0, 0);
            }
        }
        #pragma unroll
        for (int ti = 0; ti < 2; ti++) {
            int t = wave * 2 + ti;
            float bb = b1f[t * 16 + l4];
            #pragma unroll
            for (int m = 0; m < 4; m++)
                #pragma unroll
                for (int r = 0; r < 4; r++)
                    Hs[(m * 16 + quad * 4 + r) * 136 + t * 16 + l4] =
                        f2bs_t(silu(acc[ti][m][r] + bb));
        }
    }
    __syncthreads();

    // ---- GEMM2: read H1 (Hs), write H2 into Als (stride 136) ----
    {
        f32x4 acc[2][4];
        #pragma unroll
        for (int ti = 0; ti < 2; ti++)
            #pragma unroll
            for (int m = 0; m < 4; m++) acc[ti][m] = (f32x4){0,0,0,0};
        #pragma unroll
        for (int c = 0; c < 4; c++) {
            bf16x8 b0 = B2[(c * 8 + wave * 2 + 0) * 64 + lane];
            bf16x8 b1 = B2[(c * 8 + wave * 2 + 1) * 64 + lane];
            #pragma unroll
            for (int m = 0; m < 4; m++) {
                bf16x8 a = *(const bf16x8*)(&Hs[(m * 16 + l4) * 136 + c * 32 + quad * 8]);
                acc[0][m] = __builtin_amdgcn_mfma_f32_16x16x32_bf16(a, b0, acc[0][m], 0, 0, 0);
                acc[1][m] = __builtin_amdgcn_mfma_f32_16x16x32_bf16(a, b1, acc[1][m], 0, 0, 0);
            }
        }
        #pragma unroll
        for (int ti = 0; ti < 2; ti++) {
            int t = wave * 2 + ti;
            float bb = b2f[t * 16 + l4];
            #pragma unroll
            for (int m = 0; m < 4; m++)
                #pragma unroll
                for (int r = 0; r < 4; r++)
                    Als[(m * 16 + quad * 4 + r) * 136 + t * 16 + l4] =
                        f2bs_t(silu(acc[ti][m][r] + bb));
        }
    }
    __syncthreads();

    // ---- GEMM3: wave owns N-tiles {3w..3w+2}; read H2 from Als ----
    {
        f32x4 acc[3][4];
        #pragma unroll
        for (int ti = 0; ti < 3; ti++)
            #pragma unroll
            for (int m = 0; m < 4; m++) acc[ti][m] = (f32x4){0,0,0,0};
        #pragma unroll
        for (int c = 0; c < 4; c++) {
            bf16x8 b0 = B3[(c * 12 + wave * 3 + 0) * 64 + lane];
            bf16x8 b1 = B3[(c * 12 + wave * 3 + 1) * 64 + lane];
            bf16x8 b2 = B3[(c * 12 + wave * 3 + 2) * 64 + lane];
            #pragma unroll
            for (int m = 0; m < 4; m++) {
                bf16x8 a = *(const bf16x8*)(&Als[(m * 16 + l4) * 136 + c * 32 + quad * 8]);
                acc[0][m] = __builtin_amdgcn_mfma_f32_16x16x32_bf16(a, b0, acc[0][m], 0, 0, 0);
                acc[1][m] = __builtin_amdgcn_mfma_f32_16x16x32_bf16(a, b1, acc[1][m], 0, 0, 0);
                acc[2][m] = __builtin_amdgcn_mfma_f32_16x16x32_bf16(a, b2, acc[2][m], 0, 0, 0);
            }
        }
        #pragma unroll
        for (int ti = 0; ti < 3; ti++) {
            int t = wave * 3 + ti;
            float bb = b3f[t * 16 + l4];
            #pragma unroll
            for (int m = 0; m < 4; m++)
                #pragma unroll
                for (int r = 0; r < 4; r++)
                    tpx[(size_t)(e0 + m * 16 + quad * 4 + r) * 192 + t * 16 + l4] =
                        f2bs(acc[ti][m][r] + bb);
        }
    }
}

// ---------------------------------------------------------------------------
// Kernel 3: CSR aggregation + node tail. 4 waves/block, wave w owns node
// blockIdx*4+w. Inner gather loop unrolled x2 for independent load chains.
// ---------------------------------------------------------------------------
__global__ __launch_bounds__(256, 2) void node_fused_kernel(
    const int* __restrict__ base, const int* __restrict__ cnt,
    const int* __restrict__ sorted_eid, const int* __restrict__ senders,
    const float* __restrict__ vectors,
    const ushort_t* __restrict__ tpx,
    const ushort_t* __restrict__ hs_bf, const float* __restrict__ h_v,
    const int* __restrict__ specie,
    const float* __restrict__ W_dn_s, const float* __restrict__ b_dn_s,
    const float* __restrict__ W_dn_v,
    const float* __restrict__ w_sc_s, const float* __restrict__ w_sc_v,
    const float* __restrict__ W_pb_s, const float* __restrict__ b_pb_s,
    const float* __restrict__ W_pb_v,
    const float* __restrict__ W_r1_s, const float* __restrict__ b_r1_s,
    const float* __restrict__ W_r1_v,
    const float* __restrict__ W_r2_s, const float* __restrict__ b_r2,
    const float* __restrict__ W_r2_v,
    float* __restrict__ out)
{
    __shared__ float as_l[4][64];
    __shared__ float av_l[4][128][3];
    __shared__ float scs[4][64];
    __shared__ float scv[4][64][3];
    __shared__ float ps_[4][64];
    __shared__ float pv_[4][64][3];
    __shared__ int   eids[4][64];

    const int tid = threadIdx.x;
    const int w   = tid >> 6;
    const int g   = tid & 63;
    const int n   = blockIdx.x * 4 + w;

    const int b = base[n];
    const int c = cnt[n];
    float accSa = 0.f, accSb = 0.f;
    float a10a = 0.f, a11a = 0.f, a12a = 0.f;
    float a20a = 0.f, a21a = 0.f, a22a = 0.f;
    float a10b = 0.f, a11b = 0.f, a12b = 0.f;
    float a20b = 0.f, a21b = 0.f, a22b = 0.f;

    for (int done = 0; done < c; done += 64) {
        int m = min(64, c - done);
        if (g < m) eids[w][g] = sorted_eid[b + done + g];
        int i = 0;
        for (; i + 1 < m; i += 2) {
            const int e1 = eids[w][i];
            const int e2 = eids[w][i + 1];
            const int se1 = senders[e1];
            const int se2 = senders[e2];
            const float ev10 = SQ3f * vectors[e1 * 3 + 0];
            const float ev11 = SQ3f * vectors[e1 * 3 + 1];
            const float ev12 = SQ3f * vectors[e1 * 3 + 2];
            const float ev20 = SQ3f * vectors[e2 * 3 + 0];
            const float ev21 = SQ3f * vectors[e2 * 3 + 1];
            const float ev22 = SQ3f * vectors[e2 * 3 + 2];
            const float m10 = h_v[(size_t)se1 * 192 + 0 * 64 + g];
            const float m11 = h_v[(size_t)se1 * 192 + 1 * 64 + g];
            const float m12 = h_v[(size_t)se1 * 192 + 2 * 64 + g];
            const float m20 = h_v[(size_t)se2 * 192 + 0 * 64 + g];
            const float m21 = h_v[(size_t)se2 * 192 + 1 * 64 + g];
            const float m22 = h_v[(size_t)se2 * 192 + 2 * 64 + g];
            const float ms1 = bs2f(hs_bf[se1 * 64 + g]);
            const float ms2 = bs2f(hs_bf[se2 * 64 + g]);
            const ushort_t* r1 = tpx + (size_t)e1 * 192;
            const ushort_t* r2 = tpx + (size_t)e2 * 192;
            const float c10 = bs2f(r1[g]), c11 = bs2f(r1[64 + g]), c12 = bs2f(r1[128 + g]);
            const float c20 = bs2f(r2[g]), c21 = bs2f(r2[64 + g]), c22 = bs2f(r2[128 + g]);

            accSa += (m10 * ev10 + m11 * ev11 + m12 * ev12) * c10;
            accSb += (m20 * ev20 + m21 * ev21 + m22 * ev22) * c20;
            float k1a = ms1 * c11, k1b = ms2 * c21;
            a10a += k1a * ev10; a11a += k1a * ev11; a12a += k1a * ev12;
            a10b += k1b * ev20; a11b += k1b * ev21; a12b += k1b * ev22;
            a20a += (m11 * ev12 - m12 * ev11) * c12;
            a21a += (m12 * ev10 - m10 * ev12) * c12;
            a22a += (m10 * ev11 - m11 * ev10) * c12;
            a20b += (m21 * ev22 - m22 * ev21) * c22;
            a21b += (m22 * ev20 - m20 * ev22) * c22;
            a22b += (m20 * ev21 - m21 * ev20) * c22;
        }
        if (i < m) {
            const int e1 = eids[w][i];
            const int se1 = senders[e1];
            const float ev10 = SQ3f * vectors[e1 * 3 + 0];
            const float ev11 = SQ3f * vectors[e1 * 3 + 1];
            const float ev12 = SQ3f * vectors[e1 * 3 + 2];
            const float m10 = h_v[(size_t)se1 * 192 + 0 * 64 + g];
            const float m11 = h_v[(size_t)se1 * 192 + 1 * 64 + g];
            const float m12 = h_v[(size_t)se1 * 192 + 2 * 64 + g];
            const float ms1 = bs2f(hs_bf[se1 * 64 + g]);
            const ushort_t* r1 = tpx + (size_t)e1 * 192;
            const float c10 = bs2f(r1[g]), c11 = bs2f(r1[64 + g]), c12 = bs2f(r1[128 + g]);
            accSa += (m10 * ev10 + m11 * ev11 + m12 * ev12) * c10;
            float k1a = ms1 * c11;
            a10a += k1a * ev10; a11a += k1a * ev11; a12a += k1a * ev12;
            a20a += (m11 * ev12 - m12 * ev11) * c12;
            a21a += (m12 * ev10 - m10 * ev12) * c12;
            a22a += (m10 * ev11 - m11 * ev10) * c12;
        }
    }
    as_l[w][g] = (accSa + accSb) * (INV_SQ3 * INV_AVG);
    av_l[w][g][0] = (a10a + a10b) * INV_AVG;
    av_l[w][g][1] = (a11a + a11b) * INV_AVG;
    av_l[w][g][2] = (a12a + a12b) * INV_AVG;
    av_l[w][64 + g][0] = (a20a + a20b) * (INV_SQ2 * INV_AVG);
    av_l[w][64 + g][1] = (a21a + a21b) * (INV_SQ2 * INV_AVG);
    av_l[w][64 + g][2] = (a22a + a22b) * (INV_SQ2 * INV_AVG);
    // wave-private LDS; no barrier needed

    float f_s = b_dn_s[g];
    #pragma unroll 8
    for (int f = 0; f < 64; f++) f_s += as_l[w][f] * W_dn_s[f * 64 + g];
    float fv0 = 0.f, fv1 = 0.f, fv2 = 0.f;
    #pragma unroll 8
    for (int f = 0; f < 128; f++) {
        float wt = W_dn_v[f * 64 + g];
        fv0 += av_l[w][f][0] * wt;
        fv1 += av_l[w][f][1] * wt;
        fv2 += av_l[w][f][2] * wt;
    }

    float vv = (fv0 * fv0 + fv1 * fv1 + fv2 * fv2) * INV_SQ3;
    int sp = specie[n];
    float ws0 = w_sc_s[sp * 192 + 0 * 64 + g];
    float ws1 = w_sc_s[sp * 192 + 1 * 64 + g];
    float ws2 = w_sc_s[sp * 192 + 2 * 64 + g];
    float wv0 = w_sc_v[sp * 128 + 0 * 64 + g];
    float wv1 = w_sc_v[sp * 128 + 1 * 64 + g];
    float sc_s = ws0 * f_s + ws1 * f_s * f_s + ws2 * vv;
    float kv = wv0 + wv1 * f_s;
    scs[w][g] = sc_s;
    scv[w][g][0] = kv * fv0;
    scv[w][g][1] = kv * fv1;
    scv[w][g][2] = kv * fv2;

    float p_s = b_pb_s[g];
    float pv0 = 0.f, pv1 = 0.f, pv2 = 0.f;
    #pragma unroll 8
    for (int f = 0; f < 64; f++) {
        float wps = W_pb_s[f * 64 + g];
        p_s += scs[w][f] * wps;
        float wpv = W_pb_v[f * 64 + g];
        pv0 += scv[w][f][0] * wpv;
        pv1 += scv[w][f][1] * wpv;
        pv2 += scv[w][f][2] * wpv;
    }
    ps_[w][g] = p_s;
    pv_[w][g][0] = pv0; pv_[w][g][1] = pv1; pv_[w][g][2] = pv2;

    out[OFF_PS + n * 64 + g] = p_s;
    out[OFF_PV + (size_t)n * 192 + g * 3 + 0] = pv0;
    out[OFF_PV + (size_t)n * 192 + g * 3 + 1] = pv1;
    out[OFF_PV + (size_t)n * 192 + g * 3 + 2] = pv2;

    float r0 = b_r1_s[g];
    float r1 = b_r1_s[g + 64];
    float rv0 = 0.f, rv1 = 0.f, rv2 = 0.f;
    #pragma unroll 8
    for (int f = 0; f < 64; f++) {
        float p = ps_[w][f];
        r0 += p * W_r1_s[f * 128 + g];
        r1 += p * W_r1_s[f * 128 + g + 64];
        float wrv = W_r1_v[f * 64 + g];
        rv0 += pv_[w][f][0] * wrv;
        rv1 += pv_[w][f][1] * wrv;
        rv2 += pv_[w][f][2] * wrv;
    }
    float act  = silu(r0);
    float gate = silu(r1);
    float o_s = act * W_r2_s[g];
    float wr2v = W_r2_v[g];
    float ov0 = gate * rv0 * wr2v;
    float ov1 = gate * rv1 * wr2v;
    float ov2 = gate * rv2 * wr2v;

    #pragma unroll
    for (int off = 32; off > 0; off >>= 1) {
        o_s += __shfl_down(o_s, off);
        ov0 += __shfl_down(ov0, off);
        ov1 += __shfl_down(ov1, off);
        ov2 += __shfl_down(ov2, off);
    }
    if (g == 0) {
        out[OFF_OS + n] = o_s + b_r2[0];
        out[OFF_OV + n * 3 + 0] = ov0;
        out[OFF_OV + n * 3 + 1] = ov1;
        out[OFF_OV + n * 3 + 2] = ov2;
    }
}

// ---------------------------------------------------------------------------
extern "C" void kernel_launch(void* const* d_in, const int* in_sizes, int n_in,
                              void* d_out, int out_size, void* d_ws, size_t ws_size,
                              hipStream_t stream)
{
    const float* vectors  = (const float*)d_in[0];
    const float* lengths  = (const float*)d_in[1];
    const float* node_s   = (const float*)d_in[2];
    const float* node_v   = (const float*)d_in[3];
    const float* sef      = (const float*)d_in[4];
    const int*  specie    = (const int*)d_in[5];
    const int*  senders   = (const int*)d_in[6];
    const int*  receivers = (const int*)d_in[7];
    const float* W_up_s   = (const float*)d_in[8];
    const float* b_up_s   = (const float*)d_in[9];
    const float* W_up_v   = (const float*)d_in[10];
    const float* mlp_W1   = (const float*)d_in[11];
    const float* mlp_b1   = (const float*)d_in[12];
    const float* mlp_W2   = (const float*)d_in[13];
    const float* mlp_b2   = (const float*)d_in[14];
    const float* mlp_W3   = (const float*)d_in[15];
    const float* mlp_b3   = (const float*)d_in[16];
    const float* W_dn_s   = (const float*)d_in[17];
    const float* b_dn_s   = (const float*)d_in[18];
    const float* W_dn_v   = (const float*)d_in[19];
    const float* w_sc_s   = (const float*)d_in[20];
    const float* w_sc_v   = (const float*)d_in[21];
    const float* W_pb_s   = (const float*)d_in[22];
    const float* b_pb_s   = (const float*)d_in[23];
    const float* W_pb_v   = (const float*)d_in[24];
    const float* W_r1_s   = (const float*)d_in[25];
    const float* b_r1_s   = (const float*)d_in[26];
    const float* W_r1_v   = (const float*)d_in[27];
    const float* W_r2_s   = (const float*)d_in[28];
    const float* b_r2     = (const float*)d_in[29];
    const float* W_r2_v   = (const float*)d_in[30];

    float* h_v = (float*)d_ws;
    ushort_t* tpx   = (ushort_t*)(h_v + (size_t)N_ * 192);
    ushort_t* hs_bf = tpx + (size_t)E_ * 192;
    ushort_t* W1p   = hs_bf + (size_t)N_ * 64;
    ushort_t* W2p   = W1p + W1P_SZ;
    ushort_t* W3p   = W2p + W2P_SZ;
    int* cnt        = (int*)((((size_t)(W3p + W3P_SZ)) + 15) & ~(size_t)15);
    int* base       = cnt + N_;
    int* cursor     = base + N_;
    int* sorted_eid = cursor + N_;

    float* out = (float*)d_out;

    hipMemsetAsync(cnt, 0, N_ * sizeof(int), stream);

    up_kernel<<<N_ / 4, 64, 0, stream>>>(node_s, node_v, W_up_s, b_up_s, W_up_v,
                                         receivers, cnt, hs_bf, h_v);
    pack_kernel<<<256, 256, 0, stream>>>(mlp_W1, mlp_W2, mlp_W3, W1p, W2p, W3p);
    scan_kernel<<<1, 1024, 0, stream>>>(cnt, base, cursor);

    edge_mlp_kernel<<<E_ / 64, 256, 0, stream>>>(
        lengths, sef, senders, receivers,
        mlp_b1, mlp_b2, mlp_b3,
        hs_bf, W1p, W2p, W3p, cursor, sorted_eid, tpx);

    node_fused_kernel<<<N_ / 4, 256, 0, stream>>>(
        base, cnt, sorted_eid, senders, vectors,
        tpx, hs_bf, h_v, specie,
        W_dn_s, b_dn_s, W_dn_v, w_sc_s, w_sc_v,
        W_pb_s, b_pb_s, W_pb_v, W_r1_s, b_r1_s, W_r1_v,
        W_r2_s, b_r2, W_r2_v, out);
}

// Round 9
// 364.364 us; speedup vs baseline: 1.3447x; 1.0000x over previous
//
#include <hip/hip_runtime.h>

typedef short bf16x8 __attribute__((ext_vector_type(8)));
typedef float f32x4  __attribute__((ext_vector_type(4)));
typedef unsigned short ushort_t;

__device__ __forceinline__ float silu(float x) {
    float t = __expf(-x);
    return x * __builtin_amdgcn_rcpf(1.f + t);
}

__device__ __forceinline__ ushort_t f2bs(float x) {
    union { float f; unsigned int u; } v; v.f = x;
    unsigned int r = v.u + 0x7FFF + ((v.u >> 16) & 1);
    return (ushort_t)(r >> 16);
}
__device__ __forceinline__ ushort_t f2bs_t(float x) {
    union { float f; unsigned int u; } v; v.f = x;
    return (ushort_t)(v.u >> 16);
}
__device__ __forceinline__ float bs2f(ushort_t x) {
    union { unsigned int u; float f; } v; v.u = ((unsigned int)x) << 16; return v.f;
}

constexpr int N_   = 16000;
constexpr int E_   = 256000;
constexpr int Fd   = 64;

constexpr float SQ3f    = 1.7320508075688772f;
constexpr float INV_SQ3 = 0.5773502691896258f;
constexpr float INV_SQ2 = 0.7071067811865476f;
constexpr float INV_AVG = 0.0625f;

constexpr int OFF_OS = 0;
constexpr int OFF_OV = N_;
constexpr int OFF_PS = OFF_OV + 3 * N_;
constexpr int OFF_PV = OFF_PS + N_ * Fd;

constexpr int W1P_SZ = 6 * 8 * 512;
constexpr int W2P_SZ = 4 * 8 * 512;
constexpr int W3P_SZ = 4 * 12 * 512;

// ---------------------------------------------------------------------------
// pack weights fp32 -> bf16 MFMA B-fragment order
// ---------------------------------------------------------------------------
__global__ __launch_bounds__(256) void pack_kernel(
    const float* __restrict__ W1, const float* __restrict__ W2,
    const float* __restrict__ W3,
    ushort_t* __restrict__ W1p, ushort_t* __restrict__ W2p,
    ushort_t* __restrict__ W3p)
{
    int idx = blockIdx.x * 256 + threadIdx.x;
    if (idx < W1P_SZ) {
        int j = idx & 7, lane = (idx >> 3) & 63, tile = idx >> 9;
        int c = tile >> 3, t = tile & 7;
        int k = c * 32 + (lane >> 4) * 8 + j;
        int n = t * 16 + (lane & 15);
        W1p[idx] = f2bs(k < 161 ? W1[k * 128 + n] : 0.f);
    } else if (idx < W1P_SZ + W2P_SZ) {
        int q = idx - W1P_SZ;
        int j = q & 7, lane = (q >> 3) & 63, tile = q >> 9;
        int c = tile >> 3, t = tile & 7;
        int k = c * 32 + (lane >> 4) * 8 + j;
        int n = t * 16 + (lane & 15);
        W2p[q] = f2bs(W2[k * 128 + n]);
    } else {
        int q = idx - W1P_SZ - W2P_SZ;
        int j = q & 7, lane = (q >> 3) & 63, tile = q >> 9;
        int c = tile / 12, t = tile % 12;
        int k = c * 32 + (lane >> 4) * 8 + j;
        int n = t * 16 + (lane & 15);
        W3p[q] = f2bs(W3[k * 192 + n]);
    }
}

// ---------------------------------------------------------------------------
// Kernel 1: up-projection, 4 nodes/block. h_s bf16; h_v fp32 SoA.
// Fused receiver-count (64 edges/block).
// ---------------------------------------------------------------------------
__global__ __launch_bounds__(64, 4) void up_kernel(
    const float* __restrict__ node_s, const float* __restrict__ node_v,
    const float* __restrict__ W_up_s, const float* __restrict__ b_up_s,
    const float* __restrict__ W_up_v,
    const int* __restrict__ receivers, int* __restrict__ cnt,
    ushort_t* __restrict__ hs_bf, float* __restrict__ h_v)
{
    __shared__ float ns[4][64];
    __shared__ float nv[4][64][3];
    const int n0 = blockIdx.x * 4;
    const int g  = threadIdx.x;

    {
        int e = blockIdx.x * 64 + g;
        atomicAdd(&cnt[receivers[e]], 1);
    }

    #pragma unroll
    for (int j = 0; j < 4; j++) ns[j][g] = node_s[(n0 + j) * 64 + g];
    for (int idx = g; idx < 4 * 192; idx += 64) {
        int j = idx / 192, r = idx - j * 192;
        nv[j][r / 3][r % 3] = node_v[(size_t)n0 * 192 + idx];
    }
    __syncthreads();

    float as[4], a0[4], a1[4], a2[4];
    float bb = b_up_s[g];
    #pragma unroll
    for (int j = 0; j < 4; j++) { as[j] = bb; a0[j] = a1[j] = a2[j] = 0.f; }
    #pragma unroll 4
    for (int f = 0; f < 64; f++) {
        float wss = W_up_s[f * 64 + g];
        float wv  = W_up_v[f * 64 + g];
        #pragma unroll
        for (int j = 0; j < 4; j++) {
            as[j] += ns[j][f] * wss;
            a0[j] += nv[j][f][0] * wv;
            a1[j] += nv[j][f][1] * wv;
            a2[j] += nv[j][f][2] * wv;
        }
    }
    #pragma unroll
    for (int j = 0; j < 4; j++) {
        hs_bf[(n0 + j) * 64 + g] = f2bs(as[j]);
        h_v[(n0 + j) * 192 + 0 * 64 + g] = a0[j];
        h_v[(n0 + j) * 192 + 1 * 64 + g] = a1[j];
        h_v[(n0 + j) * 192 + 2 * 64 + g] = a2[j];
    }
}

// ---------------------------------------------------------------------------
// CSR scan
// ---------------------------------------------------------------------------
__global__ __launch_bounds__(1024) void scan_kernel(
    const int* __restrict__ cnt, int* __restrict__ base, int* __restrict__ cursor)
{
    __shared__ int part[1024];
    const int t = threadIdx.x;
    int v[16];
    int s = 0;
    if (t < 1000) {
        const int4* c4 = (const int4*)(cnt + t * 16);
        #pragma unroll
        for (int q = 0; q < 4; q++) {
            int4 w = c4[q];
            v[q * 4 + 0] = w.x; v[q * 4 + 1] = w.y;
            v[q * 4 + 2] = w.z; v[q * 4 + 3] = w.w;
            s += w.x + w.y + w.z + w.w;
        }
    }
    part[t] = s;
    __syncthreads();
    for (int off = 1; off < 1024; off <<= 1) {
        int u = (t >= off) ? part[t - off] : 0;
        __syncthreads();
        part[t] += u;
        __syncthreads();
    }
    if (t < 1000) {
        int run = part[t] - s;
        int b[16];
        #pragma unroll
        for (int i = 0; i < 16; i++) { b[i] = run; run += v[i]; }
        int4* bb = (int4*)(base + t * 16);
        int4* cc = (int4*)(cursor + t * 16);
        #pragma unroll
        for (int q = 0; q < 4; q++) {
            int4 w = { b[q * 4], b[q * 4 + 1], b[q * 4 + 2], b[q * 4 + 3] };
            bb[q] = w;
            cc[q] = w;
        }
    }
}

// ---------------------------------------------------------------------------
// Kernel 2: cooperative MFMA edge MLP. 256 thr = 4 waves share a 64-edge
// tile; waves split N. Mix rows are written CSR-SORTED (row perm_s[e]) so
// the aggregation kernel streams them sequentially; sorted meta {sender,
// sqrt3*ev} written alongside. Fused CSR scatter.
// ---------------------------------------------------------------------------
__global__ __launch_bounds__(256, 3) void edge_mlp_kernel(
    const float* __restrict__ lengths, const float* __restrict__ sef,
    const int* __restrict__ senders, const int* __restrict__ receivers,
    const float* __restrict__ vectors,
    const float* __restrict__ b1f, const float* __restrict__ b2f,
    const float* __restrict__ b3f,
    const ushort_t* __restrict__ hs_bf,
    const ushort_t* __restrict__ W1p, const ushort_t* __restrict__ W2p,
    const ushort_t* __restrict__ W3p,
    int* __restrict__ cursor, float4* __restrict__ meta,
    ushort_t* __restrict__ tpx)
{
    __shared__ ushort_t Als[64 * 200];  // A (GEMM1), then H2 (stride 136)
    __shared__ ushort_t Hs[64 * 136];   // H1
    __shared__ int perm_s[64];

    const int tid  = threadIdx.x;
    const int wave = tid >> 6, lane = tid & 63;
    const int quad = lane >> 4, l4 = lane & 15;
    const int e0   = blockIdx.x * 64;

    if (tid < 64) {
        int e = e0 + tid;
        int p = atomicAdd(&cursor[receivers[e]], 1);
        perm_s[tid] = p;
        float4 mt;
        mt.x = __int_as_float(senders[e]);
        mt.y = SQ3f * vectors[e * 3 + 0];
        mt.z = SQ3f * vectors[e * 3 + 1];
        mt.w = SQ3f * vectors[e * 3 + 2];
        meta[p] = mt;
    }

    // ---- stage mlp_in rows: 64 edges x 192 bf16 (pad 200), 24 chunks ----
    {
        const int e  = tid & 63;
        const int ge = e0 + e;
        const int snd = senders[ge];
        const int rcv = receivers[ge];
        for (int c = tid >> 6; c < 24; c += 4) {
            bf16x8 v;
            if (c < 8) {
                v = *(const bf16x8*)(hs_bf + snd * 64 + c * 8);
            } else if (c < 16) {
                v = *(const bf16x8*)(hs_bf + rcv * 64 + (c - 8) * 8);
            } else if (c < 20) {
                const float4 s0 = *(const float4*)(sef + (size_t)ge * 32 + (c - 16) * 8);
                const float4 s1 = *(const float4*)(sef + (size_t)ge * 32 + (c - 16) * 8 + 4);
                v[0] = (short)f2bs(s0.x); v[1] = (short)f2bs(s0.y);
                v[2] = (short)f2bs(s0.z); v[3] = (short)f2bs(s0.w);
                v[4] = (short)f2bs(s1.x); v[5] = (short)f2bs(s1.y);
                v[6] = (short)f2bs(s1.z); v[7] = (short)f2bs(s1.w);
            } else if (c == 20) {
                v = (bf16x8){0,0,0,0,0,0,0,0};
                v[0] = (short)f2bs(lengths[ge]);
            } else {
                v = (bf16x8){0,0,0,0,0,0,0,0};
            }
            *(bf16x8*)(&Als[e * 200 + c * 8]) = v;
        }
    }
    __syncthreads();

    const bf16x8* B1 = (const bf16x8*)W1p;
    const bf16x8* B2 = (const bf16x8*)W2p;
    const bf16x8* B3 = (const bf16x8*)W3p;

    // ---- GEMM1: wave owns N-tiles {2w, 2w+1}; M = 64 edges ----
    {
        f32x4 acc[2][4];
        #pragma unroll
        for (int ti = 0; ti < 2; ti++)
            #pragma unroll
            for (int m = 0; m < 4; m++) acc[ti][m] = (f32x4){0,0,0,0};
        #pragma unroll
        for (int c = 0; c < 6; c++) {
            bf16x8 b0 = B1[(c * 8 + wave * 2 + 0) * 64 + lane];
            bf16x8 b1 = B1[(c * 8 + wave * 2 + 1) * 64 + lane];
            #pragma unroll
            for (int m = 0; m < 4; m++) {
                bf16x8 a = *(const bf16x8*)(&Als[(m * 16 + l4) * 200 + c * 32 + quad * 8]);
                acc[0][m] = __builtin_amdgcn_mfma_f32_16x16x32_bf16(a, b0, acc[0][m], 0, 0, 0);
                acc[1][m] = __builtin_amdgcn_mfma_f32_16x16x32_bf16(a, b1, acc[1][m], 0, 0, 0);
            }
        }
        #pragma unroll
        for (int ti = 0; ti < 2; ti++) {
            int t = wave * 2 + ti;
            float bb = b1f[t * 16 + l4];
            #pragma unroll
            for (int m = 0; m < 4; m++)
                #pragma unroll
                for (int r = 0; r < 4; r++)
                    Hs[(m * 16 + quad * 4 + r) * 136 + t * 16 + l4] =
                        f2bs_t(silu(acc[ti][m][r] + bb));
        }
    }
    __syncthreads();

    // ---- GEMM2: read H1 (Hs), write H2 into Als (stride 136) ----
    {
        f32x4 acc[2][4];
        #pragma unroll
        for (int ti = 0; ti < 2; ti++)
            #pragma unroll
            for (int m = 0; m < 4; m++) acc[ti][m] = (f32x4){0,0,0,0};
        #pragma unroll
        for (int c = 0; c < 4; c++) {
            bf16x8 b0 = B2[(c * 8 + wave * 2 + 0) * 64 + lane];
            bf16x8 b1 = B2[(c * 8 + wave * 2 + 1) * 64 + lane];
            #pragma unroll
            for (int m = 0; m < 4; m++) {
                bf16x8 a = *(const bf16x8*)(&Hs[(m * 16 + l4) * 136 + c * 32 + quad * 8]);
                acc[0][m] = __builtin_amdgcn_mfma_f32_16x16x32_bf16(a, b0, acc[0][m], 0, 0, 0);
                acc[1][m] = __builtin_amdgcn_mfma_f32_16x16x32_bf16(a, b1, acc[1][m], 0, 0, 0);
            }
        }
        #pragma unroll
        for (int ti = 0; ti < 2; ti++) {
            int t = wave * 2 + ti;
            float bb = b2f[t * 16 + l4];
            #pragma unroll
            for (int m = 0; m < 4; m++)
                #pragma unroll
                for (int r = 0; r < 4; r++)
                    Als[(m * 16 + quad * 4 + r) * 136 + t * 16 + l4] =
                        f2bs_t(silu(acc[ti][m][r] + bb));
        }
    }
    __syncthreads();

    // ---- GEMM3: wave owns N-tiles {3w..3w+2}; stores to CSR-sorted rows ----
    {
        f32x4 acc[3][4];
        #pragma unroll
        for (int ti = 0; ti < 3; ti++)
            #pragma unroll
            for (int m = 0; m < 4; m++) acc[ti][m] = (f32x4){0,0,0,0};
        #pragma unroll
        for (int c = 0; c < 4; c++) {
            bf16x8 b0 = B3[(c * 12 + wave * 3 + 0) * 64 + lane];
            bf16x8 b1 = B3[(c * 12 + wave * 3 + 1) * 64 + lane];
            bf16x8 b2 = B3[(c * 12 + wave * 3 + 2) * 64 + lane];
            #pragma unroll
            for (int m = 0; m < 4; m++) {
                bf16x8 a = *(const bf16x8*)(&Als[(m * 16 + l4) * 136 + c * 32 + quad * 8]);
                acc[0][m] = __builtin_amdgcn_mfma_f32_16x16x32_bf16(a, b0, acc[0][m], 0, 0, 0);
                acc[1][m] = __builtin_amdgcn_mfma_f32_16x16x32_bf16(a, b1, acc[1][m], 0, 0, 0);
                acc[2][m] = __builtin_amdgcn_mfma_f32_16x16x32_bf16(a, b2, acc[2][m], 0, 0, 0);
            }
        }
        #pragma unroll
        for (int ti = 0; ti < 3; ti++) {
            int t = wave * 3 + ti;
            float bb = b3f[t * 16 + l4];
            #pragma unroll
            for (int m = 0; m < 4; m++)
                #pragma unroll
                for (int r = 0; r < 4; r++) {
                    int p = perm_s[m * 16 + quad * 4 + r];
                    tpx[(size_t)p * 192 + t * 16 + l4] = f2bs(acc[ti][m][r] + bb);
                }
        }
    }
}

// ---------------------------------------------------------------------------
// Kernel 3: CSR aggregation + node tail. 4 waves/block, wave w owns node
// blockIdx*4+w. tpx + meta are CSR-sorted -> sequential streaming; only
// h_v/hs_bf gathers (14 MB working set, L2/L3) remain random.
// ---------------------------------------------------------------------------
__global__ __launch_bounds__(256, 2) void node_fused_kernel(
    const int* __restrict__ base, const int* __restrict__ cnt,
    const float4* __restrict__ meta,
    const ushort_t* __restrict__ tpx,
    const ushort_t* __restrict__ hs_bf, const float* __restrict__ h_v,
    const int* __restrict__ specie,
    const float* __restrict__ W_dn_s, const float* __restrict__ b_dn_s,
    const float* __restrict__ W_dn_v,
    const float* __restrict__ w_sc_s, const float* __restrict__ w_sc_v,
    const float* __restrict__ W_pb_s, const float* __restrict__ b_pb_s,
    const float* __restrict__ W_pb_v,
    const float* __restrict__ W_r1_s, const float* __restrict__ b_r1_s,
    const float* __restrict__ W_r1_v,
    const float* __restrict__ W_r2_s, const float* __restrict__ b_r2,
    const float* __restrict__ W_r2_v,
    float* __restrict__ out)
{
    __shared__ float as_l[4][64];
    __shared__ float av_l[4][128][3];
    __shared__ float scs[4][64];
    __shared__ float scv[4][64][3];
    __shared__ float ps_[4][64];
    __shared__ float pv_[4][64][3];
    __shared__ float4 lmeta[4][64];

    const int tid = threadIdx.x;
    const int w   = tid >> 6;
    const int g   = tid & 63;
    const int n   = blockIdx.x * 4 + w;

    const int b = base[n];
    const int c = cnt[n];
    float accSa = 0.f, accSb = 0.f;
    float a10a = 0.f, a11a = 0.f, a12a = 0.f;
    float a20a = 0.f, a21a = 0.f, a22a = 0.f;
    float a10b = 0.f, a11b = 0.f, a12b = 0.f;
    float a20b = 0.f, a21b = 0.f, a22b = 0.f;

    for (int done = 0; done < c; done += 64) {
        int m = min(64, c - done);
        if (g < m) lmeta[w][g] = meta[b + done + g];
        int i = 0;
        for (; i + 1 < m; i += 2) {
            const float4 mt1 = lmeta[w][i];
            const float4 mt2 = lmeta[w][i + 1];
            const int se1 = __float_as_int(mt1.x);
            const int se2 = __float_as_int(mt2.x);
            const float ev10 = mt1.y, ev11 = mt1.z, ev12 = mt1.w;
            const float ev20 = mt2.y, ev21 = mt2.z, ev22 = mt2.w;
            const float m10 = h_v[(size_t)se1 * 192 + 0 * 64 + g];
            const float m11 = h_v[(size_t)se1 * 192 + 1 * 64 + g];
            const float m12 = h_v[(size_t)se1 * 192 + 2 * 64 + g];
            const float m20 = h_v[(size_t)se2 * 192 + 0 * 64 + g];
            const float m21 = h_v[(size_t)se2 * 192 + 1 * 64 + g];
            const float m22 = h_v[(size_t)se2 * 192 + 2 * 64 + g];
            const float ms1 = bs2f(hs_bf[se1 * 64 + g]);
            const float ms2 = bs2f(hs_bf[se2 * 64 + g]);
            const ushort_t* r1 = tpx + (size_t)(b + done + i) * 192;
            const ushort_t* r2 = r1 + 192;
            const float c10 = bs2f(r1[g]), c11 = bs2f(r1[64 + g]), c12 = bs2f(r1[128 + g]);
            const float c20 = bs2f(r2[g]), c21 = bs2f(r2[64 + g]), c22 = bs2f(r2[128 + g]);

            accSa += (m10 * ev10 + m11 * ev11 + m12 * ev12) * c10;
            accSb += (m20 * ev20 + m21 * ev21 + m22 * ev22) * c20;
            float k1a = ms1 * c11, k1b = ms2 * c21;
            a10a += k1a * ev10; a11a += k1a * ev11; a12a += k1a * ev12;
            a10b += k1b * ev20; a11b += k1b * ev21; a12b += k1b * ev22;
            a20a += (m11 * ev12 - m12 * ev11) * c12;
            a21a += (m12 * ev10 - m10 * ev12) * c12;
            a22a += (m10 * ev11 - m11 * ev10) * c12;
            a20b += (m21 * ev22 - m22 * ev21) * c22;
            a21b += (m22 * ev20 - m20 * ev22) * c22;
            a22b += (m20 * ev21 - m21 * ev20) * c22;
        }
        if (i < m) {
            const float4 mt1 = lmeta[w][i];
            const int se1 = __float_as_int(mt1.x);
            const float ev10 = mt1.y, ev11 = mt1.z, ev12 = mt1.w;
            const float m10 = h_v[(size_t)se1 * 192 + 0 * 64 + g];
            const float m11 = h_v[(size_t)se1 * 192 + 1 * 64 + g];
            const float m12 = h_v[(size_t)se1 * 192 + 2 * 64 + g];
            const float ms1 = bs2f(hs_bf[se1 * 64 + g]);
            const ushort_t* r1 = tpx + (size_t)(b + done + i) * 192;
            const float c10 = bs2f(r1[g]), c11 = bs2f(r1[64 + g]), c12 = bs2f(r1[128 + g]);
            accSa += (m10 * ev10 + m11 * ev11 + m12 * ev12) * c10;
            float k1a = ms1 * c11;
            a10a += k1a * ev10; a11a += k1a * ev11; a12a += k1a * ev12;
            a20a += (m11 * ev12 - m12 * ev11) * c12;
            a21a += (m12 * ev10 - m10 * ev12) * c12;
            a22a += (m10 * ev11 - m11 * ev10) * c12;
        }
    }
    as_l[w][g] = (accSa + accSb) * (INV_SQ3 * INV_AVG);
    av_l[w][g][0] = (a10a + a10b) * INV_AVG;
    av_l[w][g][1] = (a11a + a11b) * INV_AVG;
    av_l[w][g][2] = (a12a + a12b) * INV_AVG;
    av_l[w][64 + g][0] = (a20a + a20b) * (INV_SQ2 * INV_AVG);
    av_l[w][64 + g][1] = (a21a + a21b) * (INV_SQ2 * INV_AVG);
    av_l[w][64 + g][2] = (a22a + a22b) * (INV_SQ2 * INV_AVG);
    // wave-private LDS; no barrier needed

    float f_s = b_dn_s[g];
    #pragma unroll 8
    for (int f = 0; f < 64; f++) f_s += as_l[w][f] * W_dn_s[f * 64 + g];
    float fv0 = 0.f, fv1 = 0.f, fv2 = 0.f;
    #pragma unroll 8
    for (int f = 0; f < 128; f++) {
        float wt = W_dn_v[f * 64 + g];
        fv0 += av_l[w][f][0] * wt;
        fv1 += av_l[w][f][1] * wt;
        fv2 += av_l[w][f][2] * wt;
    }

    float vv = (fv0 * fv0 + fv1 * fv1 + fv2 * fv2) * INV_SQ3;
    int sp = specie[n];
    float ws0 = w_sc_s[sp * 192 + 0 * 64 + g];
    float ws1 = w_sc_s[sp * 192 + 1 * 64 + g];
    float ws2 = w_sc_s[sp * 192 + 2 * 64 + g];
    float wv0 = w_sc_v[sp * 128 + 0 * 64 + g];
    float wv1 = w_sc_v[sp * 128 + 1 * 64 + g];
    float sc_s = ws0 * f_s + ws1 * f_s * f_s + ws2 * vv;
    float kv = wv0 + wv1 * f_s;
    scs[w][g] = sc_s;
    scv[w][g][0] = kv * fv0;
    scv[w][g][1] = kv * fv1;
    scv[w][g][2] = kv * fv2;

    float p_s = b_pb_s[g];
    float pv0 = 0.f, pv1 = 0.f, pv2 = 0.f;
    #pragma unroll 8
    for (int f = 0; f < 64; f++) {
        float wps = W_pb_s[f * 64 + g];
        p_s += scs[w][f] * wps;
        float wpv = W_pb_v[f * 64 + g];
        pv0 += scv[w][f][0] * wpv;
        pv1 += scv[w][f][1] * wpv;
        pv2 += scv[w][f][2] * wpv;
    }
    ps_[w][g] = p_s;
    pv_[w][g][0] = pv0; pv_[w][g][1] = pv1; pv_[w][g][2] = pv2;

    out[OFF_PS + n * 64 + g] = p_s;
    out[OFF_PV + (size_t)n * 192 + g * 3 + 0] = pv0;
    out[OFF_PV + (size_t)n * 192 + g * 3 + 1] = pv1;
    out[OFF_PV + (size_t)n * 192 + g * 3 + 2] = pv2;

    float r0 = b_r1_s[g];
    float r1 = b_r1_s[g + 64];
    float rv0 = 0.f, rv1 = 0.f, rv2 = 0.f;
    #pragma unroll 8
    for (int f = 0; f < 64; f++) {
        float p = ps_[w][f];
        r0 += p * W_r1_s[f * 128 + g];
        r1 += p * W_r1_s[f * 128 + g + 64];
        float wrv = W_r1_v[f * 64 + g];
        rv0 += pv_[w][f][0] * wrv;
        rv1 += pv_[w][f][1] * wrv;
        rv2 += pv_[w][f][2] * wrv;
    }
    float act  = silu(r0);
    float gate = silu(r1);
    float o_s = act * W_r2_s[g];
    float wr2v = W_r2_v[g];
    float ov0 = gate * rv0 * wr2v;
    float ov1 = gate * rv1 * wr2v;
    float ov2 = gate * rv2 * wr2v;

    #pragma unroll
    for (int off = 32; off > 0; off >>= 1) {
        o_s += __shfl_down(o_s, off);
        ov0 += __shfl_down(ov0, off);
        ov1 += __shfl_down(ov1, off);
        ov2 += __shfl_down(ov2, off);
    }
    if (g == 0) {
        out[OFF_OS + n] = o_s + b_r2[0];
        out[OFF_OV + n * 3 + 0] = ov0;
        out[OFF_OV + n * 3 + 1] = ov1;
        out[OFF_OV + n * 3 + 2] = ov2;
    }
}

// ---------------------------------------------------------------------------
extern "C" void kernel_launch(void* const* d_in, const int* in_sizes, int n_in,
                              void* d_out, int out_size, void* d_ws, size_t ws_size,
                              hipStream_t stream)
{
    const float* vectors  = (const float*)d_in[0];
    const float* lengths  = (const float*)d_in[1];
    const float* node_s   = (const float*)d_in[2];
    const float* node_v   = (const float*)d_in[3];
    const float* sef      = (const float*)d_in[4];
    const int*  specie    = (const int*)d_in[5];
    const int*  senders   = (const int*)d_in[6];
    const int*  receivers = (const int*)d_in[7];
    const float* W_up_s   = (const float*)d_in[8];
    const float* b_up_s   = (const float*)d_in[9];
    const float* W_up_v   = (const float*)d_in[10];
    const float* mlp_W1   = (const float*)d_in[11];
    const float* mlp_b1   = (const float*)d_in[12];
    const float* mlp_W2   = (const float*)d_in[13];
    const float* mlp_b2   = (const float*)d_in[14];
    const float* mlp_W3   = (const float*)d_in[15];
    const float* mlp_b3   = (const float*)d_in[16];
    const float* W_dn_s   = (const float*)d_in[17];
    const float* b_dn_s   = (const float*)d_in[18];
    const float* W_dn_v   = (const float*)d_in[19];
    const float* w_sc_s   = (const float*)d_in[20];
    const float* w_sc_v   = (const float*)d_in[21];
    const float* W_pb_s   = (const float*)d_in[22];
    const float* b_pb_s   = (const float*)d_in[23];
    const float* W_pb_v   = (const float*)d_in[24];
    const float* W_r1_s   = (const float*)d_in[25];
    const float* b_r1_s   = (const float*)d_in[26];
    const float* W_r1_v   = (const float*)d_in[27];
    const float* W_r2_s   = (const float*)d_in[28];
    const float* b_r2     = (const float*)d_in[29];
    const float* W_r2_v   = (const float*)d_in[30];

    float* h_v = (float*)d_ws;                                   // N*192 f32
    ushort_t* tpx   = (ushort_t*)(h_v + (size_t)N_ * 192);       // E*192 u16
    ushort_t* hs_bf = tpx + (size_t)E_ * 192;                    // N*64 u16
    ushort_t* W1p   = hs_bf + (size_t)N_ * 64;
    ushort_t* W2p   = W1p + W1P_SZ;
    ushort_t* W3p   = W2p + W2P_SZ;
    float4* meta    = (float4*)((((size_t)(W3p + W3P_SZ)) + 15) & ~(size_t)15);  // E float4
    int* cnt        = (int*)(meta + E_);
    int* base       = cnt + N_;
    int* cursor     = base + N_;

    float* out = (float*)d_out;

    hipMemsetAsync(cnt, 0, N_ * sizeof(int), stream);

    up_kernel<<<N_ / 4, 64, 0, stream>>>(node_s, node_v, W_up_s, b_up_s, W_up_v,
                                         receivers, cnt, hs_bf, h_v);
    pack_kernel<<<256, 256, 0, stream>>>(mlp_W1, mlp_W2, mlp_W3, W1p, W2p, W3p);
    scan_kernel<<<1, 1024, 0, stream>>>(cnt, base, cursor);

    edge_mlp_kernel<<<E_ / 64, 256, 0, stream>>>(
        lengths, sef, senders, receivers, vectors,
        mlp_b1, mlp_b2, mlp_b3,
        hs_bf, W1p, W2p, W3p, cursor, meta, tpx);

    node_fused_kernel<<<N_ / 4, 256, 0, stream>>>(
        base, cnt, meta,
        tpx, hs_bf, h_v, specie,
        W_dn_s, b_dn_s, W_dn_v, w_sc_s, w_sc_v,
        W_pb_s, b_pb_s, W_pb_v, W_r1_s, b_r1_s, W_r1_v,
        W_r2_s, b_r2, W_r2_v, out);
}